// Round 1
// baseline (1342.947 us; speedup 1.0000x reference)
//
#include <hip/hip_runtime.h>
#include <stdint.h>

#define Bn 2
#define Sn 2048
#define Dn 1024
#define Hn 16
#define DKn 64
#define EDn 256

__device__ __forceinline__ float b2f(unsigned short u) {
  return __uint_as_float(((unsigned)u) << 16);
}
__device__ __forceinline__ unsigned short f2b(float x) {
  unsigned u = __float_as_uint(x);
  u += 0x7fffu + ((u >> 16) & 1u);
  return (unsigned short)(u >> 16);
}

// ---------------- Kernel 1: effective alphas ----------------
// alphas[0..15]  = 0.05/(1+||traces_h||_F)
// alphas[16..31] = 0.05/(1+||value_traces_h||_F)
__global__ __launch_bounds__(256) void k_alphas(
    const float* __restrict__ traces, const float* __restrict__ vtr,
    float* __restrict__ alphas) {
  int blk = blockIdx.x;
  const float* base;
  int n;
  if (blk < 16) { base = traces + blk * DKn * DKn; n = DKn * DKn; }
  else          { base = vtr + (blk - 16) * EDn * DKn; n = EDn * DKn; }
  float s = 0.f;
  for (int i = threadIdx.x; i < n; i += 256) { float v = base[i]; s += v * v; }
  __shared__ float red[256];
  red[threadIdx.x] = s;
  __syncthreads();
  for (int off = 128; off > 0; off >>= 1) {
    if (threadIdx.x < off) red[threadIdx.x] += red[threadIdx.x + off];
    __syncthreads();
  }
  if (threadIdx.x == 0) alphas[blk] = 0.05f / (1.f + sqrtf(red[0]));
}

// ---------------- Kernel 2/6: fp32 GEMM 128x128x16, 256 thr, 8x8/thread ----
// M=4096, N=K=1024. REMAP=true writes C in (B,H,S,DK) layout (n = h*64+dk).
template <bool REMAP>
__global__ __launch_bounds__(256) void k_gemm(
    const float* __restrict__ A, const float* __restrict__ B0,
    const float* __restrict__ B1, const float* __restrict__ B2,
    float* __restrict__ C0, float* __restrict__ C1, float* __restrict__ C2) {
  const int z = blockIdx.z;
  const float* Bm = (z == 0) ? B0 : ((z == 1) ? B1 : B2);
  float* C = (z == 0) ? C0 : ((z == 1) ? C1 : C2);
  const int tid = threadIdx.x;
  const int tx = tid & 15, ty = tid >> 4;
  const int m0 = blockIdx.y * 128;
  const int n0 = blockIdx.x * 128;

  __shared__ float As[16][132];  // transposed: As[k][m]
  __shared__ float Bs[16][132];  // Bs[k][n]

  float acc[2][4][2][4];
#pragma unroll
  for (int ri = 0; ri < 2; ++ri)
#pragma unroll
    for (int rr = 0; rr < 4; ++rr)
#pragma unroll
      for (int ci = 0; ci < 2; ++ci)
#pragma unroll
        for (int cc = 0; cc < 4; ++cc) acc[ri][rr][ci][cc] = 0.f;

  for (int k0 = 0; k0 < 1024; k0 += 16) {
    // stage A: 128 rows x 16 k, transposed into As[k][m]
#pragma unroll
    for (int i = 0; i < 2; ++i) {
      int q = tid + i * 256;      // 0..511 float4 id
      int row = q >> 2, c4 = q & 3;
      float4 a = *(const float4*)&A[(size_t)(m0 + row) * 1024 + k0 + 4 * c4];
      As[4 * c4 + 0][row] = a.x;
      As[4 * c4 + 1][row] = a.y;
      As[4 * c4 + 2][row] = a.z;
      As[4 * c4 + 3][row] = a.w;
    }
    // stage B: 16 k x 128 n
#pragma unroll
    for (int i = 0; i < 2; ++i) {
      int q = tid + i * 256;
      int kk = q >> 5, c4 = q & 31;
      float4 b = *(const float4*)&Bm[(size_t)(k0 + kk) * 1024 + n0 + 4 * c4];
      *(float4*)&Bs[kk][4 * c4] = b;
    }
    __syncthreads();
#pragma unroll
    for (int kk = 0; kk < 16; ++kk) {
      float4 a0 = *(const float4*)&As[kk][4 * ty];
      float4 a1 = *(const float4*)&As[kk][64 + 4 * ty];
      float4 b0 = *(const float4*)&Bs[kk][4 * tx];
      float4 b1 = *(const float4*)&Bs[kk][64 + 4 * tx];
      float ar[2][4] = {{a0.x, a0.y, a0.z, a0.w}, {a1.x, a1.y, a1.z, a1.w}};
      float br[2][4] = {{b0.x, b0.y, b0.z, b0.w}, {b1.x, b1.y, b1.z, b1.w}};
#pragma unroll
      for (int ri = 0; ri < 2; ++ri)
#pragma unroll
        for (int rr = 0; rr < 4; ++rr)
#pragma unroll
          for (int ci = 0; ci < 2; ++ci)
#pragma unroll
            for (int cc = 0; cc < 4; ++cc)
              acc[ri][rr][ci][cc] += ar[ri][rr] * br[ci][cc];
    }
    __syncthreads();
  }
  // write back
#pragma unroll
  for (int ri = 0; ri < 2; ++ri)
#pragma unroll
    for (int rr = 0; rr < 4; ++rr) {
      int row = m0 + ri * 64 + 4 * ty + rr;
#pragma unroll
      for (int ci = 0; ci < 2; ++ci) {
        int col = n0 + ci * 64 + 4 * tx;
        float4 v = make_float4(acc[ri][rr][ci][0], acc[ri][rr][ci][1],
                               acc[ri][rr][ci][2], acc[ri][rr][ci][3]);
        if (REMAP) {
          int b = row >> 11, s = row & 2047;
          int h = col >> 6, dk = col & 63;
          *(float4*)&C[((size_t)((b << 4) | h) * Sn + s) * DKn + dk] = v;
        } else {
          *(float4*)&C[(size_t)row * 1024 + col] = v;
        }
      }
    }
}

// ---------------- Kernel 3: pattern separation (expand+relu+top32+stored) --
// Reads RAW Q (pre-fold). Writes AT (B,S,D) = alpha_vt * stored.
__global__ __launch_bounds__(256) void k_pattsep(
    const float* __restrict__ Q, const float* __restrict__ Wexp,
    const float* __restrict__ vtr, const float* __restrict__ alphas,
    float* __restrict__ AT) {
  __shared__ unsigned short Wl[DKn * EDn];   // [d][e] bf16, 32KB
  __shared__ unsigned short VTl[EDn * DKn];  // [e][dk] bf16, 32KB
  int bh = blockIdx.x;
  int b = bh >> 4, h = bh & 15;
  int tile = blockIdx.y;

  for (int i = threadIdx.x; i < DKn * EDn; i += 256) Wl[i] = f2b(Wexp[i]);
  const float* vth = vtr + (size_t)h * EDn * DKn;
  for (int i = threadIdx.x; i < EDn * DKn; i += 256) VTl[i] = f2b(vth[i]);
  __syncthreads();

  float avt = alphas[16 + h];
  int lane = threadIdx.x & 63, w = threadIdx.x >> 6;

  for (int r = 0; r < 16; ++r) {
    int s = tile * 64 + w * 16 + r;
    float qv = (s > 0) ? Q[((size_t)bh * Sn + (s - 1)) * DKn + lane] : 0.f;
    float a0 = 0.f, a1 = 0.f, a2 = 0.f, a3 = 0.f;
#pragma unroll 8
    for (int d = 0; d < 64; ++d) {
      float qd = __shfl(qv, d);
      ushort4 wv = *(const ushort4*)&Wl[d * EDn + 4 * lane];
      a0 += qd * b2f(wv.x);
      a1 += qd * b2f(wv.y);
      a2 += qd * b2f(wv.z);
      a3 += qd * b2f(wv.w);
    }
    a0 = fmaxf(a0, 0.f); a1 = fmaxf(a1, 0.f);
    a2 = fmaxf(a2, 0.f); a3 = fmaxf(a3, 0.f);

    // 32nd-largest via binary search on float bits (all vals >= 0)
    unsigned cur = 0u;
    for (int bit = 30; bit >= 0; --bit) {
      unsigned cand = cur | (1u << bit);
      float t = __uint_as_float(cand);
      int cnt = __popcll(__ballot(a0 >= t)) + __popcll(__ballot(a1 >= t)) +
                __popcll(__ballot(a2 >= t)) + __popcll(__ballot(a3 >= t));
      if (cnt >= 32) {
        cur = cand;
        if (cnt == 32) break;
      }
    }
    float thr = __uint_as_float(cur);

    bool k0 = (a0 >= thr) && (a0 > 0.f);
    bool k1 = (a1 >= thr) && (a1 > 0.f);
    bool k2 = (a2 >= thr) && (a2 > 0.f);
    bool k3 = (a3 >= thr) && (a3 > 0.f);
    unsigned long long msk[4];
    msk[0] = __ballot(k0); msk[1] = __ballot(k1);
    msk[2] = __ballot(k2); msk[3] = __ballot(k3);
    float vals[4] = {a0, a1, a2, a3};

    float acc = 0.f;
#pragma unroll
    for (int j = 0; j < 4; ++j) {
      unsigned long long m = msk[j];
      while (m) {
        int l = __builtin_ctzll(m);
        m &= m - 1;
        float v = __shfl(vals[j], l);
        int e = l * 4 + j;
        acc += v * b2f(VTl[e * DKn + lane]);
      }
    }
    AT[((size_t)(b * Sn + s)) * Dn + h * DKn + lane] = avt * acc;
  }
}

// ---------------- Kernel 4: fold trace into Q (in-place) -------------------
// Q' = (Q + alpha_h * Q@T_h) * 0.125   (0.125 = 1/sqrt(DK) prefolded)
__global__ __launch_bounds__(256) void k_fold(
    float* __restrict__ Q, const float* __restrict__ traces,
    const float* __restrict__ alphas) {
  __shared__ float Tl[DKn * DKn];  // [d][e]
  int bh = blockIdx.x;
  int h = bh & 15;
  int tile = blockIdx.y;
  for (int i = threadIdx.x; i < DKn * DKn; i += 256)
    Tl[i] = traces[(size_t)h * DKn * DKn + i];
  __syncthreads();
  float at = alphas[h];
  int lane = threadIdx.x & 63, w = threadIdx.x >> 6;
  for (int r = 0; r < 16; ++r) {
    int s = tile * 64 + w * 16 + r;
    float* qp = Q + ((size_t)bh * Sn + s) * DKn;
    float qv = qp[lane];
    float acc = 0.f;
#pragma unroll 8
    for (int d = 0; d < 64; ++d) {
      float qd = __shfl(qv, d);
      acc += qd * Tl[d * DKn + lane];
    }
    qp[lane] = (qv + at * acc) * 0.125f;
  }
}

// ---------------- Kernel 5: flash attention (non-causal), AT += P@V --------
__global__ __launch_bounds__(256) void k_attn(
    const float* __restrict__ Qp, const float* __restrict__ Kb,
    const float* __restrict__ Vb, float* __restrict__ AT) {
  __shared__ unsigned short Qd[64][68];  // bf16, transposed [d][qrow]
  __shared__ unsigned short Kd[64][68];  // bf16, transposed [d][krow]
  __shared__ unsigned short Ps[64][68];  // bf16 [qrow][k]
  __shared__ unsigned short Vs[64][64];  // bf16 [krow][d]

  int bh = blockIdx.x;
  int b = bh >> 4, h = bh & 15;
  int qt = blockIdx.y;
  const int tid = threadIdx.x;
  const int tx = tid & 15, ty = tid >> 4;
  const float L2E = 1.4426950408889634f;

  // stage Q tile (transposed, bf16)
  const float* qg = Qp + ((size_t)bh * Sn + qt * 64) * DKn;
#pragma unroll
  for (int i = 0; i < 4; ++i) {
    int q4 = tid + i * 256;
    int row = q4 >> 4, c4 = q4 & 15;
    float4 v = *(const float4*)&qg[row * 64 + 4 * c4];
    Qd[4 * c4 + 0][row] = f2b(v.x);
    Qd[4 * c4 + 1][row] = f2b(v.y);
    Qd[4 * c4 + 2][row] = f2b(v.z);
    Qd[4 * c4 + 3][row] = f2b(v.w);
  }

  float m_i[4], l_i[4], O[4][4];
#pragma unroll
  for (int rr = 0; rr < 4; ++rr) {
    m_i[rr] = -1e30f;
    l_i[rr] = 0.f;
#pragma unroll
    for (int cc = 0; cc < 4; ++cc) O[rr][cc] = 0.f;
  }

  for (int kt = 0; kt < 32; ++kt) {
    const float* kg = Kb + ((size_t)bh * Sn + kt * 64) * DKn;
    const float* vg = Vb + ((size_t)bh * Sn + kt * 64) * DKn;
#pragma unroll
    for (int i = 0; i < 4; ++i) {
      int q4 = tid + i * 256;
      int row = q4 >> 4, c4 = q4 & 15;
      float4 kv = *(const float4*)&kg[row * 64 + 4 * c4];
      Kd[4 * c4 + 0][row] = f2b(kv.x);
      Kd[4 * c4 + 1][row] = f2b(kv.y);
      Kd[4 * c4 + 2][row] = f2b(kv.z);
      Kd[4 * c4 + 3][row] = f2b(kv.w);
      float4 vv = *(const float4*)&vg[row * 64 + 4 * c4];
      ushort4 u;
      u.x = f2b(vv.x); u.y = f2b(vv.y); u.z = f2b(vv.z); u.w = f2b(vv.w);
      *(ushort4*)&Vs[row][4 * c4] = u;
    }
    __syncthreads();

    // scores: sc[rr][cc] = q'(row 4ty+rr) . k(col 4tx+cc)   (pre-scaled)
    float sc[4][4];
#pragma unroll
    for (int rr = 0; rr < 4; ++rr)
#pragma unroll
      for (int cc = 0; cc < 4; ++cc) sc[rr][cc] = 0.f;
#pragma unroll 8
    for (int d = 0; d < 64; ++d) {
      ushort4 qa = *(const ushort4*)&Qd[d][4 * ty];
      ushort4 kb4 = *(const ushort4*)&Kd[d][4 * tx];
      float qf[4] = {b2f(qa.x), b2f(qa.y), b2f(qa.z), b2f(qa.w)};
      float kf[4] = {b2f(kb4.x), b2f(kb4.y), b2f(kb4.z), b2f(kb4.w)};
#pragma unroll
      for (int rr = 0; rr < 4; ++rr)
#pragma unroll
        for (int cc = 0; cc < 4; ++cc) sc[rr][cc] += qf[rr] * kf[cc];
    }

    // online softmax
#pragma unroll
    for (int rr = 0; rr < 4; ++rr) {
      float mt = fmaxf(fmaxf(sc[rr][0], sc[rr][1]), fmaxf(sc[rr][2], sc[rr][3]));
      mt = fmaxf(mt, __shfl_xor(mt, 1));
      mt = fmaxf(mt, __shfl_xor(mt, 2));
      mt = fmaxf(mt, __shfl_xor(mt, 4));
      mt = fmaxf(mt, __shfl_xor(mt, 8));
      float mn = fmaxf(m_i[rr], mt);
      float scale = exp2f((m_i[rr] - mn) * L2E);
      m_i[rr] = mn;
      float p[4], rs = 0.f;
#pragma unroll
      for (int cc = 0; cc < 4; ++cc) {
        p[cc] = exp2f((sc[rr][cc] - mn) * L2E);
        rs += p[cc];
      }
      rs += __shfl_xor(rs, 1);
      rs += __shfl_xor(rs, 2);
      rs += __shfl_xor(rs, 4);
      rs += __shfl_xor(rs, 8);
      l_i[rr] = l_i[rr] * scale + rs;
#pragma unroll
      for (int cc = 0; cc < 4; ++cc) O[rr][cc] *= scale;
      ushort4 pu;
      pu.x = f2b(p[0]); pu.y = f2b(p[1]); pu.z = f2b(p[2]); pu.w = f2b(p[3]);
      *(ushort4*)&Ps[4 * ty + rr][4 * tx] = pu;
    }
    __syncthreads();

    // PV: O[rr][cc] += sum_k P[row][k] * V[k][col]
#pragma unroll 4
    for (int kc = 0; kc < 16; ++kc) {
      float vf[4][4];
#pragma unroll
      for (int kk = 0; kk < 4; ++kk) {
        ushort4 u = *(const ushort4*)&Vs[4 * kc + kk][4 * tx];
        vf[kk][0] = b2f(u.x); vf[kk][1] = b2f(u.y);
        vf[kk][2] = b2f(u.z); vf[kk][3] = b2f(u.w);
      }
#pragma unroll
      for (int rr = 0; rr < 4; ++rr) {
        ushort4 pu = *(const ushort4*)&Ps[4 * ty + rr][4 * kc];
        float pf[4] = {b2f(pu.x), b2f(pu.y), b2f(pu.z), b2f(pu.w)};
#pragma unroll
        for (int kk = 0; kk < 4; ++kk)
#pragma unroll
          for (int cc = 0; cc < 4; ++cc) O[rr][cc] += pf[kk] * vf[kk][cc];
      }
    }
    __syncthreads();
  }

  // epilogue: AT += O / l
#pragma unroll
  for (int rr = 0; rr < 4; ++rr) {
    int row = qt * 64 + 4 * ty + rr;
    float inv = 1.f / l_i[rr];
    float* dst = AT + ((size_t)(b * Sn + row)) * Dn + h * DKn + 4 * tx;
    float4 old = *(float4*)dst;
    old.x += O[rr][0] * inv;
    old.y += O[rr][1] * inv;
    old.z += O[rr][2] * inv;
    old.w += O[rr][3] * inv;
    *(float4*)dst = old;
  }
}

// ---------------- launch ----------------
extern "C" void kernel_launch(void* const* d_in, const int* in_sizes, int n_in,
                              void* d_out, int out_size, void* d_ws,
                              size_t ws_size, hipStream_t stream) {
  const float* x = (const float*)d_in[0];
  const float* Wq = (const float*)d_in[1];
  const float* Wk = (const float*)d_in[2];
  const float* Wv = (const float*)d_in[3];
  const float* Wo = (const float*)d_in[4];
  const float* traces = (const float*)d_in[5];
  const float* vtr = (const float*)d_in[6];
  const float* Wexp = (const float*)d_in[7];

  float* ws = (float*)d_ws;
  const size_t NQ = (size_t)Bn * Hn * Sn * DKn;  // 4,194,304
  float* Q = ws;
  float* K = ws + NQ;
  float* V = ws + 2 * NQ;
  float* AT = ws + 3 * NQ;       // (B,S,D)
  float* alph = ws + 4 * NQ;     // 32 floats

  k_alphas<<<32, 256, 0, stream>>>(traces, vtr, alph);
  k_gemm<true><<<dim3(8, 32, 3), 256, 0, stream>>>(x, Wq, Wk, Wv, Q, K, V);
  k_pattsep<<<dim3(32, 32), 256, 0, stream>>>(Q, Wexp, vtr, alph, AT);
  k_fold<<<dim3(32, 32), 256, 0, stream>>>(Q, traces, alph);
  k_attn<<<dim3(32, 32), 256, 0, stream>>>(Q, K, V, AT);
  k_gemm<false><<<dim3(8, 32, 1), 256, 0, stream>>>(
      AT, Wo, nullptr, nullptr, (float*)d_out, nullptr, nullptr);
}

// Round 2
// 635.089 us; speedup vs baseline: 2.1146x; 2.1146x over previous
//
#include <hip/hip_runtime.h>
#include <stdint.h>

#define Bn 2
#define Sn 2048
#define Dn 1024
#define Hn 16
#define DKn 64
#define EDn 256

typedef __attribute__((ext_vector_type(8))) short bvec8;   // 8 bf16 (4 VGPR)
typedef __attribute__((ext_vector_type(4))) float fvec4;   // 4 fp32 acc

#define MFMA(a, b, c) __builtin_amdgcn_mfma_f32_16x16x32_bf16(a, b, c, 0, 0, 0)

__device__ __forceinline__ float b2f(unsigned short u) {
  return __uint_as_float(((unsigned)u) << 16);
}
__device__ __forceinline__ unsigned short f2b(float x) {
  unsigned u = __float_as_uint(x);
  u += 0x7fffu + ((u >> 16) & 1u);
  return (unsigned short)(u >> 16);
}

// ---------------- alphas: 0.05/(1+||.||_F) ----------------
__global__ __launch_bounds__(256) void k_alphas(
    const float* __restrict__ traces, const float* __restrict__ vtr,
    float* __restrict__ alphas) {
  int blk = blockIdx.x;
  const float* base;
  int n;
  if (blk < 16) { base = traces + blk * DKn * DKn; n = DKn * DKn; }
  else          { base = vtr + (blk - 16) * EDn * DKn; n = EDn * DKn; }
  float s = 0.f;
  for (int i = threadIdx.x; i < n; i += 256) { float v = base[i]; s += v * v; }
  __shared__ float red[256];
  red[threadIdx.x] = s;
  __syncthreads();
  for (int off = 128; off > 0; off >>= 1) {
    if (threadIdx.x < off) red[threadIdx.x] += red[threadIdx.x + off];
    __syncthreads();
  }
  if (threadIdx.x == 0) alphas[blk] = 0.05f / (1.f + sqrtf(red[0]));
}

// ---------------- prepass: W^T -> bf16  (Wt[n][k] = W[k][n]) ----------------
__global__ __launch_bounds__(256) void k_trW(
    const float* __restrict__ w0, const float* __restrict__ w1,
    const float* __restrict__ w2, const float* __restrict__ w3,
    unsigned short* __restrict__ dst) {
  int z = blockIdx.z;
  const float* src = (z == 0) ? w0 : ((z == 1) ? w1 : ((z == 2) ? w2 : w3));
  unsigned short* d = dst + (size_t)z * Dn * Dn;
  __shared__ unsigned short Tl[64][72];
  int tid = threadIdx.x;
  int k0 = blockIdx.y * 64, n0 = blockIdx.x * 64;
#pragma unroll
  for (int i = 0; i < 4; ++i) {
    int q = tid + 256 * i;
    int kr = q >> 4, c4 = q & 15;
    float4 v = *(const float4*)&src[(size_t)(k0 + kr) * Dn + n0 + 4 * c4];
    ushort4 u;
    u.x = f2b(v.x); u.y = f2b(v.y); u.z = f2b(v.z); u.w = f2b(v.w);
    *(ushort4*)&Tl[kr][4 * c4] = u;
  }
  __syncthreads();
#pragma unroll
  for (int i = 0; i < 4; ++i) {
    int q = tid + 256 * i;
    int nr = q >> 4, c4 = q & 15;
    ushort4 u;
    u.x = Tl[4 * c4 + 0][nr]; u.y = Tl[4 * c4 + 1][nr];
    u.z = Tl[4 * c4 + 2][nr]; u.w = Tl[4 * c4 + 3][nr];
    *(ushort4*)&d[(size_t)(n0 + nr) * Dn + k0 + 4 * c4] = u;
  }
}

// ---------------- prepass: traces^T per head -> bf16 (Tt[h][e][d]) ---------
__global__ __launch_bounds__(256) void k_trT(const float* __restrict__ tr,
                                             unsigned short* __restrict__ Tt) {
  int h = blockIdx.x;
  const float* src = tr + (size_t)h * DKn * DKn;
  unsigned short* d = Tt + (size_t)h * DKn * DKn;
  __shared__ unsigned short Tl[64][72];
  int tid = threadIdx.x;
#pragma unroll
  for (int i = 0; i < 4; ++i) {
    int q = tid + 256 * i;
    int kr = q >> 4, c4 = q & 15;
    float4 v = *(const float4*)&src[(size_t)kr * DKn + 4 * c4];
    ushort4 u;
    u.x = f2b(v.x); u.y = f2b(v.y); u.z = f2b(v.z); u.w = f2b(v.w);
    *(ushort4*)&Tl[kr][4 * c4] = u;
  }
  __syncthreads();
#pragma unroll
  for (int i = 0; i < 4; ++i) {
    int q = tid + 256 * i;
    int nr = q >> 4, c4 = q & 15;
    ushort4 u;
    u.x = Tl[4 * c4 + 0][nr]; u.y = Tl[4 * c4 + 1][nr];
    u.z = Tl[4 * c4 + 2][nr]; u.w = Tl[4 * c4 + 3][nr];
    *(ushort4*)&d[(size_t)nr * DKn + 4 * c4] = u;
  }
}

// ---------------- MFMA GEMM: 128x128 tile, BK=32, 4 waves 2x2 --------------
// MODE 0: A=x fp32 (convert in staging), 3 outputs bf16 remapped (b,h,s,dk)
// MODE 1: A=AT fp32, 1 output fp32 natural layout (d_out)
template <int MODE>
__global__ __launch_bounds__(256) void k_gemm(
    const float* __restrict__ A, const unsigned short* __restrict__ BtBase,
    unsigned short* __restrict__ Qb, unsigned short* __restrict__ Kb,
    unsigned short* __restrict__ Vb, float* __restrict__ Cout) {
  const int z = (MODE == 0) ? blockIdx.z : 0;
  const unsigned short* Bt = BtBase + (size_t)z * Dn * Dn;
  unsigned short* Cb =
      (MODE == 0) ? ((z == 0) ? Qb : ((z == 1) ? Kb : Vb)) : nullptr;
  __shared__ unsigned short As[128][40];
  __shared__ unsigned short Bs[128][40];
  const int tid = threadIdx.x;
  const int w = tid >> 6, lane = tid & 63, qd = lane >> 4, cc = lane & 15;
  const int m0 = blockIdx.y * 128, n0 = blockIdx.x * 128;
  const int mW = 64 * (w >> 1), nW = 64 * (w & 1);
  fvec4 acc[4][4];
#pragma unroll
  for (int i = 0; i < 4; ++i)
#pragma unroll
    for (int j = 0; j < 4; ++j) acc[i][j] = (fvec4){0.f, 0.f, 0.f, 0.f};

  for (int k0 = 0; k0 < Dn; k0 += 32) {
    // A: 128x32 fp32 -> bf16 LDS
#pragma unroll
    for (int i = 0; i < 4; ++i) {
      int q = tid + 256 * i;
      int row = q >> 3, c4 = q & 7;
      float4 v = *(const float4*)&A[(size_t)(m0 + row) * Dn + k0 + 4 * c4];
      ushort4 u;
      u.x = f2b(v.x); u.y = f2b(v.y); u.z = f2b(v.z); u.w = f2b(v.w);
      *(ushort4*)&As[row][4 * c4] = u;
    }
    // B: 128x32 bf16 copy (Bt is [n][k])
#pragma unroll
    for (int i = 0; i < 2; ++i) {
      int q = tid + 256 * i;
      int row = q >> 2, c8 = q & 3;
      *(uint4*)&Bs[row][8 * c8] =
          *(const uint4*)&Bt[(size_t)(n0 + row) * Dn + k0 + 8 * c8];
    }
    __syncthreads();
    bvec8 af[4], bf[4];
#pragma unroll
    for (int i = 0; i < 4; ++i) {
      af[i] = *(const bvec8*)&As[mW + 16 * i + cc][8 * qd];
      bf[i] = *(const bvec8*)&Bs[nW + 16 * i + cc][8 * qd];
    }
#pragma unroll
    for (int i = 0; i < 4; ++i)
#pragma unroll
      for (int j = 0; j < 4; ++j) acc[i][j] = MFMA(af[i], bf[j], acc[i][j]);
    __syncthreads();
  }
#pragma unroll
  for (int i = 0; i < 4; ++i)
#pragma unroll
    for (int j = 0; j < 4; ++j)
#pragma unroll
      for (int r = 0; r < 4; ++r) {
        int row = m0 + mW + 16 * i + 4 * qd + r;
        int col = n0 + nW + 16 * j + cc;
        if (MODE == 0) {
          int b = row >> 11, s = row & 2047, h = col >> 6, dk = col & 63;
          Cb[(((size_t)(b * Hn + h)) * Sn + s) * DKn + dk] = f2b(acc[i][j][r]);
        } else {
          Cout[(size_t)row * Dn + col] = acc[i][j][r];
        }
      }
}

// ---------------- V transpose: Vb[bh][s][d] -> Vt[bh][d][s] ----------------
__global__ __launch_bounds__(256) void k_vtrans(
    const unsigned short* __restrict__ Vb, unsigned short* __restrict__ Vt) {
  int bh = blockIdx.x, st = blockIdx.y;
  __shared__ unsigned short Tl[64][72];
  int tid = threadIdx.x;
#pragma unroll
  for (int i = 0; i < 4; ++i) {
    int q = tid + 256 * i;
    int sr = q >> 4, c4 = q & 15;
    *(ushort4*)&Tl[sr][4 * c4] =
        *(const ushort4*)&Vb[((size_t)bh * Sn + st * 64 + sr) * DKn + 4 * c4];
  }
  __syncthreads();
#pragma unroll
  for (int i = 0; i < 4; ++i) {
    int q = tid + 256 * i;
    int dr = q >> 4, c4 = q & 15;
    ushort4 u;
    u.x = Tl[4 * c4 + 0][dr]; u.y = Tl[4 * c4 + 1][dr];
    u.z = Tl[4 * c4 + 2][dr]; u.w = Tl[4 * c4 + 3][dr];
    *(ushort4*)&Vt[((size_t)bh * DKn + dr) * Sn + st * 64 + 4 * c4] = u;
  }
}

// ---------------- pattern separation (expand+relu+top32+stored) ------------
__global__ __launch_bounds__(256) void k_pattsep(
    const unsigned short* __restrict__ Qb, const float* __restrict__ Wexp,
    const float* __restrict__ vtr, const float* __restrict__ alphas,
    float* __restrict__ AT) {
  __shared__ unsigned short Wl[DKn * EDn];
  __shared__ unsigned short VTl[EDn * DKn];
  int bh = blockIdx.x;
  int b = bh >> 4, h = bh & 15;
  int tile = blockIdx.y;
  for (int i = threadIdx.x; i < DKn * EDn; i += 256) Wl[i] = f2b(Wexp[i]);
  const float* vth = vtr + (size_t)h * EDn * DKn;
  for (int i = threadIdx.x; i < EDn * DKn; i += 256) VTl[i] = f2b(vth[i]);
  __syncthreads();

  float avt = alphas[16 + h];
  int lane = threadIdx.x & 63, w = threadIdx.x >> 6;

  for (int r = 0; r < 64; ++r) {
    int s = tile * 256 + w * 64 + r;
    float qv = (s > 0) ? b2f(Qb[((size_t)bh * Sn + (s - 1)) * DKn + lane]) : 0.f;
    float a0 = 0.f, a1 = 0.f, a2 = 0.f, a3 = 0.f;
#pragma unroll 8
    for (int d = 0; d < 64; ++d) {
      float qd = __shfl(qv, d);
      ushort4 wv = *(const ushort4*)&Wl[d * EDn + 4 * lane];
      a0 += qd * b2f(wv.x);
      a1 += qd * b2f(wv.y);
      a2 += qd * b2f(wv.z);
      a3 += qd * b2f(wv.w);
    }
    a0 = fmaxf(a0, 0.f); a1 = fmaxf(a1, 0.f);
    a2 = fmaxf(a2, 0.f); a3 = fmaxf(a3, 0.f);

    unsigned cur = 0u;
    for (int bit = 30; bit >= 0; --bit) {
      unsigned cand = cur | (1u << bit);
      float t = __uint_as_float(cand);
      int cnt = __popcll(__ballot(a0 >= t)) + __popcll(__ballot(a1 >= t)) +
                __popcll(__ballot(a2 >= t)) + __popcll(__ballot(a3 >= t));
      if (cnt >= 32) {
        cur = cand;
        if (cnt == 32) break;
      }
    }
    float thr = __uint_as_float(cur);

    bool k0 = (a0 >= thr) && (a0 > 0.f);
    bool k1 = (a1 >= thr) && (a1 > 0.f);
    bool k2 = (a2 >= thr) && (a2 > 0.f);
    bool k3 = (a3 >= thr) && (a3 > 0.f);
    unsigned long long msk[4];
    msk[0] = __ballot(k0); msk[1] = __ballot(k1);
    msk[2] = __ballot(k2); msk[3] = __ballot(k3);
    float vals[4] = {a0, a1, a2, a3};

    float acc = 0.f;
#pragma unroll
    for (int j = 0; j < 4; ++j) {
      unsigned long long m = msk[j];
      while (m) {
        int l = __builtin_ctzll(m);
        m &= m - 1;
        float v = __shfl(vals[j], l);
        int e = l * 4 + j;
        acc += v * b2f(VTl[e * DKn + lane]);
      }
    }
    AT[((size_t)(b * Sn + s)) * Dn + h * DKn + lane] = avt * acc;
  }
}

// ---------------- fold: Qb <- (Qb + alpha * Qb@T) * 0.125 (MFMA) -----------
__global__ __launch_bounds__(256) void k_fold(
    unsigned short* __restrict__ Qb, const unsigned short* __restrict__ Tt,
    const float* __restrict__ alphas) {
  int bh = blockIdx.x, h = bh & 15, st = blockIdx.y;
  int tid = threadIdx.x;
  int w = tid >> 6, lane = tid & 63, qd = lane >> 4, cc = lane & 15;
  int s0 = st * 64 + w * 16;
  const unsigned short* qrow = Qb + ((size_t)bh * Sn + s0) * DKn;
  const unsigned short* tth = Tt + (size_t)h * DKn * DKn;
  float at = alphas[h];
  bvec8 aq0 = *(const bvec8*)&qrow[cc * DKn + 8 * qd];
  bvec8 aq1 = *(const bvec8*)&qrow[cc * DKn + 32 + 8 * qd];
  fvec4 acc[4];
#pragma unroll
  for (int j = 0; j < 4; ++j) {
    fvec4 zr = (fvec4){0.f, 0.f, 0.f, 0.f};
    bvec8 b0 = *(const bvec8*)&tth[(16 * j + cc) * DKn + 8 * qd];
    bvec8 b1 = *(const bvec8*)&tth[(16 * j + cc) * DKn + 32 + 8 * qd];
    zr = MFMA(aq0, b0, zr);
    acc[j] = MFMA(aq1, b1, zr);
  }
#pragma unroll
  for (int j = 0; j < 4; ++j)
#pragma unroll
    for (int r = 0; r < 4; ++r) {
      size_t idx = ((size_t)bh * Sn + s0 + 4 * qd + r) * DKn + 16 * j + cc;
      float q0 = b2f(Qb[idx]);
      Qb[idx] = f2b((q0 + at * acc[j][r]) * 0.125f);
    }
}

// ---------------- flash attention, MFMA, AT += P@V -------------------------
__global__ __launch_bounds__(256) void k_attn(
    const unsigned short* __restrict__ Qb, const unsigned short* __restrict__ Kb,
    const unsigned short* __restrict__ Vt, float* __restrict__ AT) {
  __shared__ unsigned short Kd[64][72];
  __shared__ unsigned short Vl[64][72];
  __shared__ unsigned short Ps[4][16][72];
  const int bh = blockIdx.x, qt = blockIdx.y;
  const int b = bh >> 4, h = bh & 15;
  const int tid = threadIdx.x;
  const int w = tid >> 6, lane = tid & 63, qd = lane >> 4, cc = lane & 15;
  const float L2E = 1.4426950408889634f;

  const unsigned short* qg = Qb + ((size_t)bh * Sn + qt * 64 + w * 16) * DKn;
  bvec8 aq0 = *(const bvec8*)&qg[cc * DKn + 8 * qd];
  bvec8 aq1 = *(const bvec8*)&qg[cc * DKn + 32 + 8 * qd];

  float m_i[4], l_i[4];
  fvec4 O[4];
#pragma unroll
  for (int r = 0; r < 4; ++r) { m_i[r] = -1e30f; l_i[r] = 0.f; }
#pragma unroll
  for (int j = 0; j < 4; ++j) O[j] = (fvec4){0.f, 0.f, 0.f, 0.f};

  for (int kt = 0; kt < Sn / 64; ++kt) {
    __syncthreads();
#pragma unroll
    for (int i = 0; i < 4; ++i) {
      int q = tid + 256 * i;
      int r = q >> 4, c4 = q & 15;
      *(ushort4*)&Kd[r][4 * c4] =
          *(const ushort4*)&Kb[((size_t)bh * Sn + kt * 64 + r) * DKn + 4 * c4];
      *(ushort4*)&Vl[r][4 * c4] =
          *(const ushort4*)&Vt[((size_t)bh * DKn + r) * Sn + kt * 64 + 4 * c4];
    }
    __syncthreads();
    fvec4 sc[4];
#pragma unroll
    for (int j = 0; j < 4; ++j) {
      fvec4 zr = (fvec4){0.f, 0.f, 0.f, 0.f};
      bvec8 b0 = *(const bvec8*)&Kd[16 * j + cc][8 * qd];
      bvec8 b1 = *(const bvec8*)&Kd[16 * j + cc][32 + 8 * qd];
      zr = MFMA(aq0, b0, zr);
      sc[j] = MFMA(aq1, b1, zr);
    }
    // online softmax (rows r = 4*qd + r, reduce across quad's 16 lanes)
#pragma unroll
    for (int r = 0; r < 4; ++r) {
      float v = fmaxf(fmaxf(sc[0][r], sc[1][r]), fmaxf(sc[2][r], sc[3][r]));
      v = fmaxf(v, __shfl_xor(v, 1));
      v = fmaxf(v, __shfl_xor(v, 2));
      v = fmaxf(v, __shfl_xor(v, 4));
      v = fmaxf(v, __shfl_xor(v, 8));
      float mn = fmaxf(m_i[r], v);
      float scale = exp2f((m_i[r] - mn) * L2E);
      m_i[r] = mn;
      float rs = 0.f;
#pragma unroll
      for (int j = 0; j < 4; ++j) {
        float p = exp2f((sc[j][r] - mn) * L2E);
        Ps[w][4 * qd + r][16 * j + cc] = f2b(p);
        rs += p;
      }
      rs += __shfl_xor(rs, 1);
      rs += __shfl_xor(rs, 2);
      rs += __shfl_xor(rs, 4);
      rs += __shfl_xor(rs, 8);
      l_i[r] = l_i[r] * scale + rs;
#pragma unroll
      for (int j = 0; j < 4; ++j) O[j][r] *= scale;
    }
    // PV: P through LDS (C-layout -> A-layout), V from transposed tile
    bvec8 ap0 = *(const bvec8*)&Ps[w][cc][8 * qd];
    bvec8 ap1 = *(const bvec8*)&Ps[w][cc][32 + 8 * qd];
#pragma unroll
    for (int j = 0; j < 4; ++j) {
      bvec8 v0 = *(const bvec8*)&Vl[16 * j + cc][8 * qd];
      bvec8 v1 = *(const bvec8*)&Vl[16 * j + cc][32 + 8 * qd];
      O[j] = MFMA(ap0, v0, O[j]);
      O[j] = MFMA(ap1, v1, O[j]);
    }
  }
  float inv[4];
#pragma unroll
  for (int r = 0; r < 4; ++r) inv[r] = 1.f / l_i[r];
#pragma unroll
  for (int j = 0; j < 4; ++j)
#pragma unroll
    for (int r = 0; r < 4; ++r) {
      int row = qt * 64 + w * 16 + 4 * qd + r;
      float* p = AT + ((size_t)(b * Sn + row)) * Dn + h * DKn + 16 * j + cc;
      *p += O[j][r] * inv[r];
    }
}

// ---------------- launch ----------------
extern "C" void kernel_launch(void* const* d_in, const int* in_sizes, int n_in,
                              void* d_out, int out_size, void* d_ws,
                              size_t ws_size, hipStream_t stream) {
  const float* x = (const float*)d_in[0];
  const float* Wq = (const float*)d_in[1];
  const float* Wk = (const float*)d_in[2];
  const float* Wv = (const float*)d_in[3];
  const float* Wo = (const float*)d_in[4];
  const float* traces = (const float*)d_in[5];
  const float* vtr = (const float*)d_in[6];
  const float* Wexp = (const float*)d_in[7];

  const size_t NQ = (size_t)Bn * Hn * Sn * DKn;  // 4,194,304
  unsigned short* Qb = (unsigned short*)d_ws;
  unsigned short* Kb = Qb + NQ;
  unsigned short* Vb = Kb + NQ;
  unsigned short* Vt = Vb + NQ;
  unsigned short* Wt = Vt + NQ;               // 4 x 1M bf16 = NQ shorts
  unsigned short* Tt = Wt + NQ;               // 16*64*64 = 65536
  float* alph = (float*)(Tt + 65536);         // 32 floats
  float* AT = alph + 32;                      // (B,S,D) fp32, 16MB

  k_trW<<<dim3(16, 16, 4), 256, 0, stream>>>(Wq, Wk, Wv, Wo, Wt);
  k_trT<<<16, 256, 0, stream>>>(traces, Tt);
  k_alphas<<<32, 256, 0, stream>>>(traces, vtr, alph);
  k_gemm<0><<<dim3(8, 32, 3), 256, 0, stream>>>(x, Wt, Qb, Kb, Vb, nullptr);
  k_vtrans<<<dim3(32, 32), 256, 0, stream>>>(Vb, Vt);
  k_pattsep<<<dim3(32, 8), 256, 0, stream>>>(Qb, Wexp, vtr, alph, AT);
  k_fold<<<dim3(32, 32), 256, 0, stream>>>(Qb, Tt, alph);
  k_attn<<<dim3(32, 32), 256, 0, stream>>>(Qb, Kb, Vt, AT);
  k_gemm<1><<<dim3(8, 32, 1), 256, 0, stream>>>(AT, Wt + 3 * (size_t)Dn * Dn,
                                                nullptr, nullptr, nullptr,
                                                (float*)d_out);
}

// Round 3
// 431.278 us; speedup vs baseline: 3.1139x; 1.4726x over previous
//
#include <hip/hip_runtime.h>
#include <stdint.h>

#define Bn 2
#define Sn 2048
#define Dn 1024
#define Hn 16
#define DKn 64
#define EDn 256

typedef __attribute__((ext_vector_type(8))) short bvec8;   // 8 bf16 (4 VGPR)
typedef __attribute__((ext_vector_type(4))) float fvec4;   // 4 fp32 acc

#define MFMA(a, b, c) __builtin_amdgcn_mfma_f32_16x16x32_bf16(a, b, c, 0, 0, 0)

__device__ __forceinline__ float b2f(unsigned short u) {
  return __uint_as_float(((unsigned)u) << 16);
}
__device__ __forceinline__ unsigned short f2b(float x) {
  unsigned u = __float_as_uint(x);
  u += 0x7fffu + ((u >> 16) & 1u);
  return (unsigned short)(u >> 16);
}

// ---------------- alphas: 0.05/(1+||.||_F) ----------------
__global__ __launch_bounds__(256) void k_alphas(
    const float* __restrict__ traces, const float* __restrict__ vtr,
    float* __restrict__ alphas) {
  int blk = blockIdx.x;
  const float* base;
  int n;
  if (blk < 16) { base = traces + blk * DKn * DKn; n = DKn * DKn; }
  else          { base = vtr + (blk - 16) * EDn * DKn; n = EDn * DKn; }
  float s = 0.f;
  for (int i = threadIdx.x; i < n; i += 256) { float v = base[i]; s += v * v; }
  __shared__ float red[256];
  red[threadIdx.x] = s;
  __syncthreads();
  for (int off = 128; off > 0; off >>= 1) {
    if (threadIdx.x < off) red[threadIdx.x] += red[threadIdx.x + off];
    __syncthreads();
  }
  if (threadIdx.x == 0) alphas[blk] = 0.05f / (1.f + sqrtf(red[0]));
}

// ---------------- prepass: W^T -> bf16  (Wt[n][k] = W[k][n]) ----------------
__global__ __launch_bounds__(256) void k_trW(
    const float* __restrict__ w0, const float* __restrict__ w1,
    const float* __restrict__ w2, const float* __restrict__ w3,
    unsigned short* __restrict__ dst) {
  int z = blockIdx.z;
  const float* src = (z == 0) ? w0 : ((z == 1) ? w1 : ((z == 2) ? w2 : w3));
  unsigned short* d = dst + (size_t)z * Dn * Dn;
  __shared__ unsigned short Tl[64][72];
  int tid = threadIdx.x;
  int k0 = blockIdx.y * 64, n0 = blockIdx.x * 64;
#pragma unroll
  for (int i = 0; i < 4; ++i) {
    int q = tid + 256 * i;
    int kr = q >> 4, c4 = q & 15;
    float4 v = *(const float4*)&src[(size_t)(k0 + kr) * Dn + n0 + 4 * c4];
    ushort4 u;
    u.x = f2b(v.x); u.y = f2b(v.y); u.z = f2b(v.z); u.w = f2b(v.w);
    *(ushort4*)&Tl[kr][4 * c4] = u;
  }
  __syncthreads();
#pragma unroll
  for (int i = 0; i < 4; ++i) {
    int q = tid + 256 * i;
    int nr = q >> 4, c4 = q & 15;
    ushort4 u;
    u.x = Tl[4 * c4 + 0][nr]; u.y = Tl[4 * c4 + 1][nr];
    u.z = Tl[4 * c4 + 2][nr]; u.w = Tl[4 * c4 + 3][nr];
    *(ushort4*)&d[(size_t)(n0 + nr) * Dn + k0 + 4 * c4] = u;
  }
}

// ---------------- prepass: traces^T per head -> bf16 (Tt[h][e][d]) ---------
__global__ __launch_bounds__(256) void k_trT(const float* __restrict__ tr,
                                             unsigned short* __restrict__ Tt) {
  int h = blockIdx.x;
  const float* src = tr + (size_t)h * DKn * DKn;
  unsigned short* d = Tt + (size_t)h * DKn * DKn;
  __shared__ unsigned short Tl[64][72];
  int tid = threadIdx.x;
#pragma unroll
  for (int i = 0; i < 4; ++i) {
    int q = tid + 256 * i;
    int kr = q >> 4, c4 = q & 15;
    float4 v = *(const float4*)&src[(size_t)kr * DKn + 4 * c4];
    ushort4 u;
    u.x = f2b(v.x); u.y = f2b(v.y); u.z = f2b(v.z); u.w = f2b(v.w);
    *(ushort4*)&Tl[kr][4 * c4] = u;
  }
  __syncthreads();
#pragma unroll
  for (int i = 0; i < 4; ++i) {
    int q = tid + 256 * i;
    int nr = q >> 4, c4 = q & 15;
    ushort4 u;
    u.x = Tl[4 * c4 + 0][nr]; u.y = Tl[4 * c4 + 1][nr];
    u.z = Tl[4 * c4 + 2][nr]; u.w = Tl[4 * c4 + 3][nr];
    *(ushort4*)&d[(size_t)nr * DKn + 4 * c4] = u;
  }
}

// ---------------- prepass: Wexp[64][256] -> WexpT[256][64] bf16 ------------
__global__ __launch_bounds__(256) void k_trE(const float* __restrict__ Wexp,
                                             unsigned short* __restrict__ WexpT) {
  int e0 = blockIdx.x * 64;
  __shared__ unsigned short Tl[64][72];
  int tid = threadIdx.x;
#pragma unroll
  for (int i = 0; i < 4; ++i) {
    int q = tid + 256 * i;
    int dr = q >> 4, c4 = q & 15;
    float4 v = *(const float4*)&Wexp[(size_t)dr * EDn + e0 + 4 * c4];
    ushort4 u;
    u.x = f2b(v.x); u.y = f2b(v.y); u.z = f2b(v.z); u.w = f2b(v.w);
    *(ushort4*)&Tl[dr][4 * c4] = u;
  }
  __syncthreads();
#pragma unroll
  for (int i = 0; i < 4; ++i) {
    int q = tid + 256 * i;
    int er = q >> 4, c4 = q & 15;
    ushort4 u;
    u.x = Tl[4 * c4 + 0][er]; u.y = Tl[4 * c4 + 1][er];
    u.z = Tl[4 * c4 + 2][er]; u.w = Tl[4 * c4 + 3][er];
    *(ushort4*)&WexpT[(size_t)(e0 + er) * DKn + 4 * c4] = u;
  }
}

// ---------------- prepass: vtr[h][256][64] -> VTt[h][64][256] bf16 ---------
__global__ __launch_bounds__(256) void k_trVT(const float* __restrict__ vtr,
                                              unsigned short* __restrict__ VTt) {
  int e0 = blockIdx.x * 64;
  int h = blockIdx.y;
  const float* src = vtr + (size_t)h * EDn * DKn;
  unsigned short* dst = VTt + (size_t)h * DKn * EDn;
  __shared__ unsigned short Tl[64][72];
  int tid = threadIdx.x;
#pragma unroll
  for (int i = 0; i < 4; ++i) {
    int q = tid + 256 * i;
    int er = q >> 4, c4 = q & 15;
    float4 v = *(const float4*)&src[(size_t)(e0 + er) * DKn + 4 * c4];
    ushort4 u;
    u.x = f2b(v.x); u.y = f2b(v.y); u.z = f2b(v.z); u.w = f2b(v.w);
    *(ushort4*)&Tl[er][4 * c4] = u;
  }
  __syncthreads();
#pragma unroll
  for (int i = 0; i < 4; ++i) {
    int q = tid + 256 * i;
    int dr = q >> 4, c4 = q & 15;
    ushort4 u;
    u.x = Tl[4 * c4 + 0][dr]; u.y = Tl[4 * c4 + 1][dr];
    u.z = Tl[4 * c4 + 2][dr]; u.w = Tl[4 * c4 + 3][dr];
    *(ushort4*)&dst[(size_t)dr * EDn + e0 + 4 * c4] = u;
  }
}

// ---------------- MFMA GEMM: 128x128 tile, BK=32, 4 waves 2x2 --------------
template <int MODE>
__global__ __launch_bounds__(256) void k_gemm(
    const float* __restrict__ A, const unsigned short* __restrict__ BtBase,
    unsigned short* __restrict__ Qb, unsigned short* __restrict__ Kb,
    unsigned short* __restrict__ Vb, float* __restrict__ Cout) {
  const int z = (MODE == 0) ? blockIdx.z : 0;
  const unsigned short* Bt = BtBase + (size_t)z * Dn * Dn;
  unsigned short* Cb =
      (MODE == 0) ? ((z == 0) ? Qb : ((z == 1) ? Kb : Vb)) : nullptr;
  __shared__ unsigned short As[128][40];
  __shared__ unsigned short Bs[128][40];
  const int tid = threadIdx.x;
  const int w = tid >> 6, lane = tid & 63, qd = lane >> 4, cc = lane & 15;
  const int m0 = blockIdx.y * 128, n0 = blockIdx.x * 128;
  const int mW = 64 * (w >> 1), nW = 64 * (w & 1);
  fvec4 acc[4][4];
#pragma unroll
  for (int i = 0; i < 4; ++i)
#pragma unroll
    for (int j = 0; j < 4; ++j) acc[i][j] = (fvec4){0.f, 0.f, 0.f, 0.f};

  for (int k0 = 0; k0 < Dn; k0 += 32) {
#pragma unroll
    for (int i = 0; i < 4; ++i) {
      int q = tid + 256 * i;
      int row = q >> 3, c4 = q & 7;
      float4 v = *(const float4*)&A[(size_t)(m0 + row) * Dn + k0 + 4 * c4];
      ushort4 u;
      u.x = f2b(v.x); u.y = f2b(v.y); u.z = f2b(v.z); u.w = f2b(v.w);
      *(ushort4*)&As[row][4 * c4] = u;
    }
#pragma unroll
    for (int i = 0; i < 2; ++i) {
      int q = tid + 256 * i;
      int row = q >> 2, c8 = q & 3;
      *(uint4*)&Bs[row][8 * c8] =
          *(const uint4*)&Bt[(size_t)(n0 + row) * Dn + k0 + 8 * c8];
    }
    __syncthreads();
    bvec8 af[4], bf[4];
#pragma unroll
    for (int i = 0; i < 4; ++i) {
      af[i] = *(const bvec8*)&As[mW + 16 * i + cc][8 * qd];
      bf[i] = *(const bvec8*)&Bs[nW + 16 * i + cc][8 * qd];
    }
#pragma unroll
    for (int i = 0; i < 4; ++i)
#pragma unroll
      for (int j = 0; j < 4; ++j) acc[i][j] = MFMA(af[i], bf[j], acc[i][j]);
    __syncthreads();
  }
#pragma unroll
  for (int i = 0; i < 4; ++i)
#pragma unroll
    for (int j = 0; j < 4; ++j)
#pragma unroll
      for (int r = 0; r < 4; ++r) {
        int row = m0 + mW + 16 * i + 4 * qd + r;
        int col = n0 + nW + 16 * j + cc;
        if (MODE == 0) {
          int b = row >> 11, s = row & 2047, h = col >> 6, dk = col & 63;
          Cb[(((size_t)(b * Hn + h)) * Sn + s) * DKn + dk] = f2b(acc[i][j][r]);
        } else {
          Cout[(size_t)row * Dn + col] = acc[i][j][r];
        }
      }
}

// ---------------- V transpose: Vb[bh][s][d] -> Vt[bh][d][s] ----------------
__global__ __launch_bounds__(256) void k_vtrans(
    const unsigned short* __restrict__ Vb, unsigned short* __restrict__ Vt) {
  int bh = blockIdx.x, st = blockIdx.y;
  __shared__ unsigned short Tl[64][72];
  int tid = threadIdx.x;
#pragma unroll
  for (int i = 0; i < 4; ++i) {
    int q = tid + 256 * i;
    int sr = q >> 4, c4 = q & 15;
    *(ushort4*)&Tl[sr][4 * c4] =
        *(const ushort4*)&Vb[((size_t)bh * Sn + st * 64 + sr) * DKn + 4 * c4];
  }
  __syncthreads();
#pragma unroll
  for (int i = 0; i < 4; ++i) {
    int q = tid + 256 * i;
    int dr = q >> 4, c4 = q & 15;
    ushort4 u;
    u.x = Tl[4 * c4 + 0][dr]; u.y = Tl[4 * c4 + 1][dr];
    u.z = Tl[4 * c4 + 2][dr]; u.w = Tl[4 * c4 + 3][dr];
    *(ushort4*)&Vt[((size_t)bh * DKn + dr) * Sn + st * 64 + 4 * c4] = u;
  }
}

// ---------------- pattern separation: MFMA expand + quad top-k + MFMA read -
// grid (tile=32, bh=32), 256 thr. Each wave: 16 rows.
__global__ __launch_bounds__(256) void k_pattsep(
    const unsigned short* __restrict__ Qb,
    const unsigned short* __restrict__ WexpT,  // [256][64] bf16
    const unsigned short* __restrict__ VTt,    // [16][64][256] bf16
    const float* __restrict__ alphas, float* __restrict__ AT) {
  __shared__ unsigned short Ps[4][16][264];
  const int tile = blockIdx.x, bh = blockIdx.y;
  const int b = bh >> 4, h = bh & 15;
  const int tid = threadIdx.x;
  const int w = tid >> 6, lane = tid & 63, qd = lane >> 4, cc = lane & 15;
  const int s0 = tile * 64 + w * 16;
  const float avt = alphas[16 + h];

  // A-frags: Qprev row (s0+cc-1); zero row for s==0
  const int srow = s0 + cc;
  bvec8 aq0 = {}, aq1 = {};
  if (srow > 0) {
    const unsigned short* qp = Qb + ((size_t)bh * Sn + srow - 1) * DKn;
    aq0 = *(const bvec8*)&qp[8 * qd];
    aq1 = *(const bvec8*)&qp[32 + 8 * qd];
  }
  // expand: E[j] covers cols 16j+cc, rows 4qd+r
  fvec4 E[16];
#pragma unroll 4
  for (int j = 0; j < 16; ++j) {
    const unsigned short* wp = WexpT + (size_t)(16 * j + cc) * DKn;
    bvec8 b0 = *(const bvec8*)&wp[8 * qd];
    bvec8 b1 = *(const bvec8*)&wp[32 + 8 * qd];
    fvec4 z = {0.f, 0.f, 0.f, 0.f};
    z = MFMA(aq0, b0, z);
    E[j] = MFMA(aq1, b1, z);
  }
#pragma unroll
  for (int j = 0; j < 16; ++j)
#pragma unroll
    for (int r = 0; r < 4; ++r) E[j][r] = fmaxf(E[j][r], 0.f);

  // per-row 32nd-largest via bit binary search; 4 rows (quads) in parallel
#pragma unroll
  for (int r = 0; r < 4; ++r) {
    unsigned cur = 0u;
    bool done = false;
    for (int bit = 30; bit >= 0; --bit) {
      unsigned cand = cur | (1u << bit);
      float t = __uint_as_float(cand);
      int cnt = 0;
#pragma unroll
      for (int j = 0; j < 16; ++j) cnt += (E[j][r] >= t) ? 1 : 0;
      cnt += __shfl_xor(cnt, 1);
      cnt += __shfl_xor(cnt, 2);
      cnt += __shfl_xor(cnt, 4);
      cnt += __shfl_xor(cnt, 8);
      if (!done && cnt >= 32) {
        cur = cand;
        if (cnt == 32) done = true;
      }
      if (__all(done)) break;
    }
    float thr = __uint_as_float(cur);
#pragma unroll
    for (int j = 0; j < 16; ++j) {
      float v = E[j][r];
      bool sel = (v >= thr) && (v > 0.f);
      Ps[w][4 * qd + r][16 * j + cc] = sel ? f2b(v) : (unsigned short)0;
    }
  }

  // stored = P @ VTt_h^T : 16 rows x 64 d, K=256
  const unsigned short* vt = VTt + (size_t)h * DKn * EDn;
  bvec8 ap[8];
#pragma unroll
  for (int c = 0; c < 8; ++c)
    ap[c] = *(const bvec8*)&Ps[w][cc][32 * c + 8 * qd];
  fvec4 acc2[4];
#pragma unroll
  for (int j2 = 0; j2 < 4; ++j2) {
    fvec4 z = {0.f, 0.f, 0.f, 0.f};
    const unsigned short* vp = vt + (size_t)(16 * j2 + cc) * EDn;
#pragma unroll
    for (int c = 0; c < 8; ++c) {
      bvec8 bv = *(const bvec8*)&vp[32 * c + 8 * qd];
      z = MFMA(ap[c], bv, z);
    }
    acc2[j2] = z;
  }
#pragma unroll
  for (int j2 = 0; j2 < 4; ++j2)
#pragma unroll
    for (int r = 0; r < 4; ++r) {
      int row = s0 + 4 * qd + r;
      AT[((size_t)(b * Sn + row)) * Dn + h * DKn + 16 * j2 + cc] =
          avt * acc2[j2][r];
    }
}

// ---------------- fold: Qb <- (Qb + alpha * Qb@T) * 0.125 (MFMA) -----------
__global__ __launch_bounds__(256) void k_fold(
    unsigned short* __restrict__ Qb, const unsigned short* __restrict__ Tt,
    const float* __restrict__ alphas) {
  int bh = blockIdx.x, h = bh & 15, st = blockIdx.y;
  int tid = threadIdx.x;
  int w = tid >> 6, lane = tid & 63, qd = lane >> 4, cc = lane & 15;
  int s0 = st * 64 + w * 16;
  const unsigned short* qrow = Qb + ((size_t)bh * Sn + s0) * DKn;
  const unsigned short* tth = Tt + (size_t)h * DKn * DKn;
  float at = alphas[h];
  bvec8 aq0 = *(const bvec8*)&qrow[cc * DKn + 8 * qd];
  bvec8 aq1 = *(const bvec8*)&qrow[cc * DKn + 32 + 8 * qd];
  fvec4 acc[4];
#pragma unroll
  for (int j = 0; j < 4; ++j) {
    fvec4 zr = (fvec4){0.f, 0.f, 0.f, 0.f};
    bvec8 b0 = *(const bvec8*)&tth[(16 * j + cc) * DKn + 8 * qd];
    bvec8 b1 = *(const bvec8*)&tth[(16 * j + cc) * DKn + 32 + 8 * qd];
    zr = MFMA(aq0, b0, zr);
    acc[j] = MFMA(aq1, b1, zr);
  }
#pragma unroll
  for (int j = 0; j < 4; ++j)
#pragma unroll
    for (int r = 0; r < 4; ++r) {
      size_t idx = ((size_t)bh * Sn + s0 + 4 * qd + r) * DKn + 16 * j + cc;
      float q0 = b2f(Qb[idx]);
      Qb[idx] = f2b((q0 + at * acc[j][r]) * 0.125f);
    }
}

// ---------------- flash attention, MFMA, AT += P@V -------------------------
__global__ __launch_bounds__(256) void k_attn(
    const unsigned short* __restrict__ Qb, const unsigned short* __restrict__ Kb,
    const unsigned short* __restrict__ Vt, float* __restrict__ AT) {
  __shared__ unsigned short Kd[64][72];
  __shared__ unsigned short Vl[64][72];
  __shared__ unsigned short Ps[4][16][72];
  const int bh = blockIdx.x, qt = blockIdx.y;
  const int b = bh >> 4, h = bh & 15;
  const int tid = threadIdx.x;
  const int w = tid >> 6, lane = tid & 63, qd = lane >> 4, cc = lane & 15;
  const float L2E = 1.4426950408889634f;

  const unsigned short* qg = Qb + ((size_t)bh * Sn + qt * 64 + w * 16) * DKn;
  bvec8 aq0 = *(const bvec8*)&qg[cc * DKn + 8 * qd];
  bvec8 aq1 = *(const bvec8*)&qg[cc * DKn + 32 + 8 * qd];

  float m_i[4], l_i[4];
  fvec4 O[4];
#pragma unroll
  for (int r = 0; r < 4; ++r) { m_i[r] = -1e30f; l_i[r] = 0.f; }
#pragma unroll
  for (int j = 0; j < 4; ++j) O[j] = (fvec4){0.f, 0.f, 0.f, 0.f};

  for (int kt = 0; kt < Sn / 64; ++kt) {
    __syncthreads();
#pragma unroll
    for (int i = 0; i < 4; ++i) {
      int q = tid + 256 * i;
      int r = q >> 4, c4 = q & 15;
      *(ushort4*)&Kd[r][4 * c4] =
          *(const ushort4*)&Kb[((size_t)bh * Sn + kt * 64 + r) * DKn + 4 * c4];
      *(ushort4*)&Vl[r][4 * c4] =
          *(const ushort4*)&Vt[((size_t)bh * DKn + r) * Sn + kt * 64 + 4 * c4];
    }
    __syncthreads();
    fvec4 sc[4];
#pragma unroll
    for (int j = 0; j < 4; ++j) {
      fvec4 zr = (fvec4){0.f, 0.f, 0.f, 0.f};
      bvec8 b0 = *(const bvec8*)&Kd[16 * j + cc][8 * qd];
      bvec8 b1 = *(const bvec8*)&Kd[16 * j + cc][32 + 8 * qd];
      zr = MFMA(aq0, b0, zr);
      sc[j] = MFMA(aq1, b1, zr);
    }
#pragma unroll
    for (int r = 0; r < 4; ++r) {
      float v = fmaxf(fmaxf(sc[0][r], sc[1][r]), fmaxf(sc[2][r], sc[3][r]));
      v = fmaxf(v, __shfl_xor(v, 1));
      v = fmaxf(v, __shfl_xor(v, 2));
      v = fmaxf(v, __shfl_xor(v, 4));
      v = fmaxf(v, __shfl_xor(v, 8));
      float mn = fmaxf(m_i[r], v);
      float scale = exp2f((m_i[r] - mn) * L2E);
      m_i[r] = mn;
      float rs = 0.f;
#pragma unroll
      for (int j = 0; j < 4; ++j) {
        float p = exp2f((sc[j][r] - mn) * L2E);
        Ps[w][4 * qd + r][16 * j + cc] = f2b(p);
        rs += p;
      }
      rs += __shfl_xor(rs, 1);
      rs += __shfl_xor(rs, 2);
      rs += __shfl_xor(rs, 4);
      rs += __shfl_xor(rs, 8);
      l_i[r] = l_i[r] * scale + rs;
#pragma unroll
      for (int j = 0; j < 4; ++j) O[j][r] *= scale;
    }
    bvec8 ap0 = *(const bvec8*)&Ps[w][cc][8 * qd];
    bvec8 ap1 = *(const bvec8*)&Ps[w][cc][32 + 8 * qd];
#pragma unroll
    for (int j = 0; j < 4; ++j) {
      bvec8 v0 = *(const bvec8*)&Vl[16 * j + cc][8 * qd];
      bvec8 v1 = *(const bvec8*)&Vl[16 * j + cc][32 + 8 * qd];
      O[j] = MFMA(ap0, v0, O[j]);
      O[j] = MFMA(ap1, v1, O[j]);
    }
  }
  float inv[4];
#pragma unroll
  for (int r = 0; r < 4; ++r) inv[r] = 1.f / l_i[r];
#pragma unroll
  for (int j = 0; j < 4; ++j)
#pragma unroll
    for (int r = 0; r < 4; ++r) {
      int row = qt * 64 + w * 16 + 4 * qd + r;
      float* p = AT + ((size_t)(b * Sn + row)) * Dn + h * DKn + 16 * j + cc;
      *p += O[j][r] * inv[r];
    }
}

// ---------------- launch ----------------
extern "C" void kernel_launch(void* const* d_in, const int* in_sizes, int n_in,
                              void* d_out, int out_size, void* d_ws,
                              size_t ws_size, hipStream_t stream) {
  const float* x = (const float*)d_in[0];
  const float* Wq = (const float*)d_in[1];
  const float* Wk = (const float*)d_in[2];
  const float* Wv = (const float*)d_in[3];
  const float* Wo = (const float*)d_in[4];
  const float* traces = (const float*)d_in[5];
  const float* vtr = (const float*)d_in[6];
  const float* Wexp = (const float*)d_in[7];

  const size_t NQ = (size_t)Bn * Hn * Sn * DKn;  // 4,194,304
  unsigned short* Qb = (unsigned short*)d_ws;
  unsigned short* Kb = Qb + NQ;
  unsigned short* Vb = Kb + NQ;
  unsigned short* Vt = Vb + NQ;
  unsigned short* Wt = Vt + NQ;                // 4 x D*D bf16 = NQ shorts
  unsigned short* Tt = Wt + NQ;                // 16*64*64 = 65536
  unsigned short* WexpT = Tt + 65536;          // 256*64 = 16384
  unsigned short* VTt = WexpT + 16384;         // 16*64*256 = 262144
  float* alph = (float*)(VTt + 262144);        // 32 floats
  float* AT = alph + 32;                       // (B,S,D) fp32, 16MB

  k_trW<<<dim3(16, 16, 4), 256, 0, stream>>>(Wq, Wk, Wv, Wo, Wt);
  k_trT<<<16, 256, 0, stream>>>(traces, Tt);
  k_trE<<<4, 256, 0, stream>>>(Wexp, WexpT);
  k_trVT<<<dim3(4, 16), 256, 0, stream>>>(vtr, VTt);
  k_alphas<<<32, 256, 0, stream>>>(traces, vtr, alph);
  k_gemm<0><<<dim3(8, 32, 3), 256, 0, stream>>>(x, Wt, Qb, Kb, Vb, nullptr);
  k_vtrans<<<dim3(32, 32), 256, 0, stream>>>(Vb, Vt);
  k_pattsep<<<dim3(32, 32), 256, 0, stream>>>(Qb, WexpT, VTt, alph, AT);
  k_fold<<<dim3(32, 32), 256, 0, stream>>>(Qb, Tt, alph);
  k_attn<<<dim3(32, 32), 256, 0, stream>>>(Qb, Kb, Vt, AT);
  k_gemm<1><<<dim3(8, 32, 1), 256, 0, stream>>>(AT, Wt + 3 * (size_t)Dn * Dn,
                                                nullptr, nullptr, nullptr,
                                                (float*)d_out);
}

// Round 4
// 376.426 us; speedup vs baseline: 3.5676x; 1.1457x over previous
//
#include <hip/hip_runtime.h>
#include <stdint.h>

#define Bn 2
#define Sn 2048
#define Dn 1024
#define Hn 16
#define DKn 64
#define EDn 256

typedef __attribute__((ext_vector_type(8))) short bvec8;   // 8 bf16 (4 VGPR)
typedef __attribute__((ext_vector_type(4))) float fvec4;   // 4 fp32 acc

#define MFMA(a, b, c) __builtin_amdgcn_mfma_f32_16x16x32_bf16(a, b, c, 0, 0, 0)

__device__ __forceinline__ float b2f(unsigned short u) {
  return __uint_as_float(((unsigned)u) << 16);
}
__device__ __forceinline__ unsigned short f2b(float x) {
  unsigned u = __float_as_uint(x);
  u += 0x7fffu + ((u >> 16) & 1u);
  return (unsigned short)(u >> 16);
}

// ---------------- alphas: 0.05/(1+||.||_F) ----------------
__global__ __launch_bounds__(256) void k_alphas(
    const float* __restrict__ traces, const float* __restrict__ vtr,
    float* __restrict__ alphas) {
  int blk = blockIdx.x;
  const float* base;
  int n;
  if (blk < 16) { base = traces + blk * DKn * DKn; n = DKn * DKn; }
  else          { base = vtr + (blk - 16) * EDn * DKn; n = EDn * DKn; }
  float s = 0.f;
  for (int i = threadIdx.x; i < n; i += 256) { float v = base[i]; s += v * v; }
  __shared__ float red[256];
  red[threadIdx.x] = s;
  __syncthreads();
  for (int off = 128; off > 0; off >>= 1) {
    if (threadIdx.x < off) red[threadIdx.x] += red[threadIdx.x + off];
    __syncthreads();
  }
  if (threadIdx.x == 0) alphas[blk] = 0.05f / (1.f + sqrtf(red[0]));
}

// ---------------- prepass: W^T -> bf16  (Wt[n][k] = W[k][n]) ----------------
__global__ __launch_bounds__(256) void k_trW(
    const float* __restrict__ w0, const float* __restrict__ w1,
    const float* __restrict__ w2, const float* __restrict__ w3,
    unsigned short* __restrict__ dst) {
  int z = blockIdx.z;
  const float* src = (z == 0) ? w0 : ((z == 1) ? w1 : ((z == 2) ? w2 : w3));
  unsigned short* d = dst + (size_t)z * Dn * Dn;
  __shared__ unsigned short Tl[64][72];
  int tid = threadIdx.x;
  int k0 = blockIdx.y * 64, n0 = blockIdx.x * 64;
#pragma unroll
  for (int i = 0; i < 4; ++i) {
    int q = tid + 256 * i;
    int kr = q >> 4, c4 = q & 15;
    float4 v = *(const float4*)&src[(size_t)(k0 + kr) * Dn + n0 + 4 * c4];
    ushort4 u;
    u.x = f2b(v.x); u.y = f2b(v.y); u.z = f2b(v.z); u.w = f2b(v.w);
    *(ushort4*)&Tl[kr][4 * c4] = u;
  }
  __syncthreads();
#pragma unroll
  for (int i = 0; i < 4; ++i) {
    int q = tid + 256 * i;
    int nr = q >> 4, c4 = q & 15;
    ushort4 u;
    u.x = Tl[4 * c4 + 0][nr]; u.y = Tl[4 * c4 + 1][nr];
    u.z = Tl[4 * c4 + 2][nr]; u.w = Tl[4 * c4 + 3][nr];
    *(ushort4*)&d[(size_t)(n0 + nr) * Dn + k0 + 4 * c4] = u;
  }
}

// ---------------- prepass: Mt[h][e][k] = 0.125*(I + alpha_h*T_h)[k][e] -----
__global__ __launch_bounds__(256) void k_mkM(const float* __restrict__ tr,
                                             const float* __restrict__ alph,
                                             unsigned short* __restrict__ Mt) {
  int h = blockIdx.x;
  float a = alph[h] * 0.125f;
  const float* th = tr + (size_t)h * DKn * DKn;
  unsigned short* mh = Mt + (size_t)h * DKn * DKn;
  for (int i = threadIdx.x; i < DKn * DKn; i += 256) {
    int e = i >> 6, k = i & 63;
    float v = a * th[(size_t)k * DKn + e] + ((e == k) ? 0.125f : 0.f);
    mh[i] = f2b(v);
  }
}

// ---------------- prepass: Wexp[64][256] -> WexpT[256][64] bf16 ------------
__global__ __launch_bounds__(256) void k_trE(const float* __restrict__ Wexp,
                                             unsigned short* __restrict__ WexpT) {
  int e0 = blockIdx.x * 64;
  __shared__ unsigned short Tl[64][72];
  int tid = threadIdx.x;
#pragma unroll
  for (int i = 0; i < 4; ++i) {
    int q = tid + 256 * i;
    int dr = q >> 4, c4 = q & 15;
    float4 v = *(const float4*)&Wexp[(size_t)dr * EDn + e0 + 4 * c4];
    ushort4 u;
    u.x = f2b(v.x); u.y = f2b(v.y); u.z = f2b(v.z); u.w = f2b(v.w);
    *(ushort4*)&Tl[dr][4 * c4] = u;
  }
  __syncthreads();
#pragma unroll
  for (int i = 0; i < 4; ++i) {
    int q = tid + 256 * i;
    int er = q >> 4, c4 = q & 15;
    ushort4 u;
    u.x = Tl[4 * c4 + 0][er]; u.y = Tl[4 * c4 + 1][er];
    u.z = Tl[4 * c4 + 2][er]; u.w = Tl[4 * c4 + 3][er];
    *(ushort4*)&WexpT[(size_t)(e0 + er) * DKn + 4 * c4] = u;
  }
}

// ---------------- prepass: vtr[h][256][64] -> VTt[h][64][256] bf16 ---------
__global__ __launch_bounds__(256) void k_trVT(const float* __restrict__ vtr,
                                              unsigned short* __restrict__ VTt) {
  int e0 = blockIdx.x * 64;
  int h = blockIdx.y;
  const float* src = vtr + (size_t)h * EDn * DKn;
  unsigned short* dst = VTt + (size_t)h * DKn * EDn;
  __shared__ unsigned short Tl[64][72];
  int tid = threadIdx.x;
#pragma unroll
  for (int i = 0; i < 4; ++i) {
    int q = tid + 256 * i;
    int er = q >> 4, c4 = q & 15;
    float4 v = *(const float4*)&src[(size_t)(e0 + er) * DKn + 4 * c4];
    ushort4 u;
    u.x = f2b(v.x); u.y = f2b(v.y); u.z = f2b(v.z); u.w = f2b(v.w);
    *(ushort4*)&Tl[er][4 * c4] = u;
  }
  __syncthreads();
#pragma unroll
  for (int i = 0; i < 4; ++i) {
    int q = tid + 256 * i;
    int dr = q >> 4, c4 = q & 15;
    ushort4 u;
    u.x = Tl[4 * c4 + 0][dr]; u.y = Tl[4 * c4 + 1][dr];
    u.z = Tl[4 * c4 + 2][dr]; u.w = Tl[4 * c4 + 3][dr];
    *(ushort4*)&dst[(size_t)dr * EDn + e0 + 4 * c4] = u;
  }
}

// ---------------- prepass: x fp32 -> bf16 ----------------------------------
__global__ __launch_bounds__(256) void k_xb(const float* __restrict__ x,
                                            unsigned short* __restrict__ xb) {
  size_t i = ((size_t)blockIdx.x * 256 + threadIdx.x) * 4;
  float4 v = *(const float4*)&x[i];
  ushort4 u;
  u.x = f2b(v.x); u.y = f2b(v.y); u.z = f2b(v.z); u.w = f2b(v.w);
  *(ushort4*)&xb[i] = u;
}

// ---------------- MFMA GEMM: 128x128 tile, BK=32, 4 waves 2x2 --------------
// MODE 0: A bf16, 3 outputs bf16 remapped (b,h,s,dk). MODE 1: A fp32, C fp32.
template <int MODE>
__global__ __launch_bounds__(256) void k_gemm(
    const unsigned short* __restrict__ Ab, const float* __restrict__ Af,
    const unsigned short* __restrict__ BtBase, unsigned short* __restrict__ Qb,
    unsigned short* __restrict__ Kb, unsigned short* __restrict__ Vb,
    float* __restrict__ Cout) {
  const int z = (MODE == 0) ? blockIdx.z : 0;
  const unsigned short* Bt = BtBase + (size_t)z * Dn * Dn;
  unsigned short* Cb =
      (MODE == 0) ? ((z == 0) ? Qb : ((z == 1) ? Kb : Vb)) : nullptr;
  __shared__ unsigned short As[128][40];
  __shared__ unsigned short Bs[128][40];
  const int tid = threadIdx.x;
  const int w = tid >> 6, lane = tid & 63, qd = lane >> 4, cc = lane & 15;
  const int m0 = blockIdx.y * 128, n0 = blockIdx.x * 128;
  const int mW = 64 * (w >> 1), nW = 64 * (w & 1);
  fvec4 acc[4][4];
#pragma unroll
  for (int i = 0; i < 4; ++i)
#pragma unroll
    for (int j = 0; j < 4; ++j) acc[i][j] = (fvec4){0.f, 0.f, 0.f, 0.f};

  for (int k0 = 0; k0 < Dn; k0 += 32) {
    if (MODE == 0) {
#pragma unroll
      for (int i = 0; i < 2; ++i) {
        int q = tid + 256 * i;
        int row = q >> 2, c8 = q & 3;
        *(uint4*)&As[row][8 * c8] =
            *(const uint4*)&Ab[(size_t)(m0 + row) * Dn + k0 + 8 * c8];
      }
    } else {
#pragma unroll
      for (int i = 0; i < 4; ++i) {
        int q = tid + 256 * i;
        int row = q >> 3, c4 = q & 7;
        float4 v = *(const float4*)&Af[(size_t)(m0 + row) * Dn + k0 + 4 * c4];
        ushort4 u;
        u.x = f2b(v.x); u.y = f2b(v.y); u.z = f2b(v.z); u.w = f2b(v.w);
        *(ushort4*)&As[row][4 * c4] = u;
      }
    }
#pragma unroll
    for (int i = 0; i < 2; ++i) {
      int q = tid + 256 * i;
      int row = q >> 2, c8 = q & 3;
      *(uint4*)&Bs[row][8 * c8] =
          *(const uint4*)&Bt[(size_t)(n0 + row) * Dn + k0 + 8 * c8];
    }
    __syncthreads();
    bvec8 af[4], bf[4];
#pragma unroll
    for (int i = 0; i < 4; ++i) {
      af[i] = *(const bvec8*)&As[mW + 16 * i + cc][8 * qd];
      bf[i] = *(const bvec8*)&Bs[nW + 16 * i + cc][8 * qd];
    }
#pragma unroll
    for (int i = 0; i < 4; ++i)
#pragma unroll
      for (int j = 0; j < 4; ++j) acc[i][j] = MFMA(af[i], bf[j], acc[i][j]);
    __syncthreads();
  }
#pragma unroll
  for (int i = 0; i < 4; ++i)
#pragma unroll
    for (int j = 0; j < 4; ++j)
#pragma unroll
      for (int r = 0; r < 4; ++r) {
        int row = m0 + mW + 16 * i + 4 * qd + r;
        int col = n0 + nW + 16 * j + cc;
        if (MODE == 0) {
          int b = row >> 11, s = row & 2047, h = col >> 6, dk = col & 63;
          Cb[(((size_t)(b * Hn + h)) * Sn + s) * DKn + dk] = f2b(acc[i][j][r]);
        } else {
          Cout[(size_t)row * Dn + col] = acc[i][j][r];
        }
      }
}

// ---------------- V transpose: Vb[bh][s][d] -> Vt[bh][d][s] ----------------
__global__ __launch_bounds__(256) void k_vtrans(
    const unsigned short* __restrict__ Vb, unsigned short* __restrict__ Vt) {
  int bh = blockIdx.x, st = blockIdx.y;
  __shared__ unsigned short Tl[64][72];
  int tid = threadIdx.x;
#pragma unroll
  for (int i = 0; i < 4; ++i) {
    int q = tid + 256 * i;
    int sr = q >> 4, c4 = q & 15;
    *(ushort4*)&Tl[sr][4 * c4] =
        *(const ushort4*)&Vb[((size_t)bh * Sn + st * 64 + sr) * DKn + 4 * c4];
  }
  __syncthreads();
#pragma unroll
  for (int i = 0; i < 4; ++i) {
    int q = tid + 256 * i;
    int dr = q >> 4, c4 = q & 15;
    ushort4 u;
    u.x = Tl[4 * c4 + 0][dr]; u.y = Tl[4 * c4 + 1][dr];
    u.z = Tl[4 * c4 + 2][dr]; u.w = Tl[4 * c4 + 3][dr];
    *(ushort4*)&Vt[((size_t)bh * DKn + dr) * Sn + st * 64 + 4 * c4] = u;
  }
}

// ---------------- pattern separation: MFMA expand + quad top-k + MFMA read -
__global__ __launch_bounds__(256) void k_pattsep(
    const unsigned short* __restrict__ Qb,
    const unsigned short* __restrict__ WexpT,  // [256][64] bf16
    const unsigned short* __restrict__ VTt,    // [16][64][256] bf16
    const float* __restrict__ alphas, float* __restrict__ AT) {
  __shared__ unsigned short Ps[4][16][264];
  const int tile = blockIdx.x, bh = blockIdx.y;
  const int b = bh >> 4, h = bh & 15;
  const int tid = threadIdx.x;
  const int w = tid >> 6, lane = tid & 63, qd = lane >> 4, cc = lane & 15;
  const int s0 = tile * 64 + w * 16;
  const float avt = alphas[16 + h];

  const int srow = s0 + cc;
  bvec8 aq0 = {}, aq1 = {};
  if (srow > 0) {
    const unsigned short* qp = Qb + ((size_t)bh * Sn + srow - 1) * DKn;
    aq0 = *(const bvec8*)&qp[8 * qd];
    aq1 = *(const bvec8*)&qp[32 + 8 * qd];
  }
  fvec4 E[16];
#pragma unroll 4
  for (int j = 0; j < 16; ++j) {
    const unsigned short* wp = WexpT + (size_t)(16 * j + cc) * DKn;
    bvec8 b0 = *(const bvec8*)&wp[8 * qd];
    bvec8 b1 = *(const bvec8*)&wp[32 + 8 * qd];
    fvec4 z = {0.f, 0.f, 0.f, 0.f};
    z = MFMA(aq0, b0, z);
    E[j] = MFMA(aq1, b1, z);
  }
#pragma unroll
  for (int j = 0; j < 16; ++j)
#pragma unroll
    for (int r = 0; r < 4; ++r) E[j][r] = fmaxf(E[j][r], 0.f);

#pragma unroll
  for (int r = 0; r < 4; ++r) {
    unsigned cur = 0u;
    bool done = false;
    for (int bit = 30; bit >= 0; --bit) {
      unsigned cand = cur | (1u << bit);
      float t = __uint_as_float(cand);
      int cnt = 0;
#pragma unroll
      for (int j = 0; j < 16; ++j) cnt += (E[j][r] >= t) ? 1 : 0;
      cnt += __shfl_xor(cnt, 1);
      cnt += __shfl_xor(cnt, 2);
      cnt += __shfl_xor(cnt, 4);
      cnt += __shfl_xor(cnt, 8);
      if (!done && cnt >= 32) {
        cur = cand;
        if (cnt == 32) done = true;
      }
      if (__all(done)) break;
    }
    float thr = __uint_as_float(cur);
#pragma unroll
    for (int j = 0; j < 16; ++j) {
      float v = E[j][r];
      bool sel = (v >= thr) && (v > 0.f);
      Ps[w][4 * qd + r][16 * j + cc] = sel ? f2b(v) : (unsigned short)0;
    }
  }

  const unsigned short* vt = VTt + (size_t)h * DKn * EDn;
  bvec8 ap[8];
#pragma unroll
  for (int c = 0; c < 8; ++c)
    ap[c] = *(const bvec8*)&Ps[w][cc][32 * c + 8 * qd];
  fvec4 acc2[4];
#pragma unroll
  for (int j2 = 0; j2 < 4; ++j2) {
    fvec4 z = {0.f, 0.f, 0.f, 0.f};
    const unsigned short* vp = vt + (size_t)(16 * j2 + cc) * EDn;
#pragma unroll
    for (int c = 0; c < 8; ++c) {
      bvec8 bv = *(const bvec8*)&vp[32 * c + 8 * qd];
      z = MFMA(ap[c], bv, z);
    }
    acc2[j2] = z;
  }
#pragma unroll
  for (int j2 = 0; j2 < 4; ++j2)
#pragma unroll
    for (int r = 0; r < 4; ++r) {
      int row = s0 + 4 * qd + r;
      AT[((size_t)(b * Sn + row)) * Dn + h * DKn + 16 * j2 + cc] =
          avt * acc2[j2][r];
    }
}

// ---------------- flash attention + fused fold, fixed-max softmax ----------
__global__ __launch_bounds__(256) void k_attn(
    const unsigned short* __restrict__ Qb, const unsigned short* __restrict__ Kb,
    const unsigned short* __restrict__ Vt, const unsigned short* __restrict__ Mt,
    float* __restrict__ AT) {
  __shared__ unsigned short Kd[64][72];
  __shared__ unsigned short Vl[64][72];
  __shared__ unsigned short Ps[4][16][72];
  const int bh = blockIdx.x, qt = blockIdx.y;
  const int b = bh >> 4, h = bh & 15;
  const int tid = threadIdx.x;
  const int w = tid >> 6, lane = tid & 63, qd = lane >> 4, cc = lane & 15;
  const float L2E = 1.4426950408889634f;
  const float NB = 23.083120654223414f;  // 16*log2(e)

  // fused fold: Q' = Qraw @ M, M = 0.125*(I + alpha*T), via Mt[h][e][k]
  const unsigned short* qg = Qb + ((size_t)bh * Sn + qt * 64 + w * 16) * DKn;
  bvec8 a0 = *(const bvec8*)&qg[cc * DKn + 8 * qd];
  bvec8 a1 = *(const bvec8*)&qg[cc * DKn + 32 + 8 * qd];
  const unsigned short* mh = Mt + (size_t)h * DKn * DKn;
  unsigned short(*Qd)[72] = &Kd[16 * w];  // reuse Kd before first barrier
#pragma unroll
  for (int j = 0; j < 4; ++j) {
    bvec8 b0 = *(const bvec8*)&mh[(size_t)(16 * j + cc) * DKn + 8 * qd];
    bvec8 b1 = *(const bvec8*)&mh[(size_t)(16 * j + cc) * DKn + 32 + 8 * qd];
    fvec4 z = {0.f, 0.f, 0.f, 0.f};
    z = MFMA(a0, b0, z);
    z = MFMA(a1, b1, z);
#pragma unroll
    for (int r = 0; r < 4; ++r) Qd[4 * qd + r][16 * j + cc] = f2b(z[r]);
  }
  bvec8 aq0 = *(const bvec8*)&Qd[cc][8 * qd];
  bvec8 aq1 = *(const bvec8*)&Qd[cc][32 + 8 * qd];

  float l_i[4] = {0.f, 0.f, 0.f, 0.f};
  fvec4 O[4];
#pragma unroll
  for (int j = 0; j < 4; ++j) O[j] = (fvec4){0.f, 0.f, 0.f, 0.f};

  for (int kt = 0; kt < Sn / 64; ++kt) {
    __syncthreads();
#pragma unroll
    for (int i = 0; i < 2; ++i) {
      int q = tid + 256 * i;
      int r = q >> 3, c8 = q & 7;
      *(uint4*)&Kd[r][8 * c8] =
          *(const uint4*)&Kb[((size_t)bh * Sn + kt * 64 + r) * DKn + 8 * c8];
      *(uint4*)&Vl[r][8 * c8] =
          *(const uint4*)&Vt[((size_t)bh * DKn + r) * Sn + kt * 64 + 8 * c8];
    }
    __syncthreads();
    fvec4 sc[4];
#pragma unroll
    for (int j = 0; j < 4; ++j) {
      bvec8 b0 = *(const bvec8*)&Kd[16 * j + cc][8 * qd];
      bvec8 b1 = *(const bvec8*)&Kd[16 * j + cc][32 + 8 * qd];
      fvec4 z = {0.f, 0.f, 0.f, 0.f};
      z = MFMA(aq0, b0, z);
      sc[j] = MFMA(aq1, b1, z);
    }
    // fixed-offset softmax: p = e^(s-16); common factor cancels in O/l
#pragma unroll
    for (int j = 0; j < 4; ++j)
#pragma unroll
      for (int r = 0; r < 4; ++r) {
        float p = exp2f(fmaf(sc[j][r], L2E, -NB));
        l_i[r] += p;
        Ps[w][4 * qd + r][16 * j + cc] = f2b(p);
      }
    bvec8 ap0 = *(const bvec8*)&Ps[w][cc][8 * qd];
    bvec8 ap1 = *(const bvec8*)&Ps[w][cc][32 + 8 * qd];
#pragma unroll
    for (int j = 0; j < 4; ++j) {
      bvec8 v0 = *(const bvec8*)&Vl[16 * j + cc][8 * qd];
      bvec8 v1 = *(const bvec8*)&Vl[16 * j + cc][32 + 8 * qd];
      O[j] = MFMA(ap0, v0, O[j]);
      O[j] = MFMA(ap1, v1, O[j]);
    }
  }
#pragma unroll
  for (int r = 0; r < 4; ++r) {
    l_i[r] += __shfl_xor(l_i[r], 1);
    l_i[r] += __shfl_xor(l_i[r], 2);
    l_i[r] += __shfl_xor(l_i[r], 4);
    l_i[r] += __shfl_xor(l_i[r], 8);
  }
  float inv[4];
#pragma unroll
  for (int r = 0; r < 4; ++r) inv[r] = 1.f / l_i[r];
#pragma unroll
  for (int j = 0; j < 4; ++j)
#pragma unroll
    for (int r = 0; r < 4; ++r) {
      int row = qt * 64 + w * 16 + 4 * qd + r;
      float* p = AT + ((size_t)(b * Sn + row)) * Dn + h * DKn + 16 * j + cc;
      *p += O[j][r] * inv[r];
    }
}

// ---------------- launch ----------------
extern "C" void kernel_launch(void* const* d_in, const int* in_sizes, int n_in,
                              void* d_out, int out_size, void* d_ws,
                              size_t ws_size, hipStream_t stream) {
  const float* x = (const float*)d_in[0];
  const float* Wq = (const float*)d_in[1];
  const float* Wk = (const float*)d_in[2];
  const float* Wv = (const float*)d_in[3];
  const float* Wo = (const float*)d_in[4];
  const float* traces = (const float*)d_in[5];
  const float* vtr = (const float*)d_in[6];
  const float* Wexp = (const float*)d_in[7];

  const size_t NQ = (size_t)Bn * Hn * Sn * DKn;  // 4,194,304
  unsigned short* Qb = (unsigned short*)d_ws;
  unsigned short* Kb = Qb + NQ;
  unsigned short* Vb = Kb + NQ;
  unsigned short* Vt = Vb + NQ;
  unsigned short* Wt = Vt + NQ;                // 4 x D*D bf16 = NQ shorts
  unsigned short* Mt = Wt + NQ;                // 16*64*64 = 65536
  unsigned short* WexpT = Mt + 65536;          // 256*64 = 16384
  unsigned short* VTt = WexpT + 16384;         // 16*64*256 = 262144
  float* alph = (float*)(VTt + 262144);        // 32 floats
  float* AT = alph + 32;                       // (B,S,D) fp32, 16MB
  unsigned short* xb = (unsigned short*)AT;    // aliased: dead before pattsep

  k_alphas<<<32, 256, 0, stream>>>(traces, vtr, alph);
  k_trW<<<dim3(16, 16, 4), 256, 0, stream>>>(Wq, Wk, Wv, Wo, Wt);
  k_mkM<<<16, 256, 0, stream>>>(traces, alph, Mt);
  k_trE<<<4, 256, 0, stream>>>(Wexp, WexpT);
  k_trVT<<<dim3(4, 16), 256, 0, stream>>>(vtr, VTt);
  k_xb<<<4096, 256, 0, stream>>>(x, xb);
  k_gemm<0><<<dim3(8, 32, 3), 256, 0, stream>>>(xb, nullptr, Wt, Qb, Kb, Vb,
                                                nullptr);
  k_vtrans<<<dim3(32, 32), 256, 0, stream>>>(Vb, Vt);
  k_pattsep<<<dim3(32, 32), 256, 0, stream>>>(Qb, WexpT, VTt, alph, AT);
  k_attn<<<dim3(32, 32), 256, 0, stream>>>(Qb, Kb, Vt, Mt, AT);
  k_gemm<1><<<dim3(8, 32, 1), 256, 0, stream>>>(
      nullptr, AT, Wt + 3 * (size_t)Dn * Dn, nullptr, nullptr, nullptr,
      (float*)d_out);
}

// Round 5
// 338.548 us; speedup vs baseline: 3.9668x; 1.1119x over previous
//
#include <hip/hip_runtime.h>
#include <stdint.h>

#define Bn 2
#define Sn 2048
#define Dn 1024
#define Hn 16
#define DKn 64
#define EDn 256

typedef __attribute__((ext_vector_type(8))) short bvec8;   // 8 bf16 (4 VGPR)
typedef __attribute__((ext_vector_type(4))) float fvec4;   // 4 fp32 acc

#define MFMA(a, b, c) __builtin_amdgcn_mfma_f32_16x16x32_bf16(a, b, c, 0, 0, 0)

__device__ __forceinline__ float b2f(unsigned short u) {
  return __uint_as_float(((unsigned)u) << 16);
}
__device__ __forceinline__ unsigned short f2b(float x) {
  unsigned u = __float_as_uint(x);
  u += 0x7fffu + ((u >> 16) & 1u);
  return (unsigned short)(u >> 16);
}

// ---------------- alphas: 0.05/(1+||.||_F) ----------------
__global__ __launch_bounds__(256) void k_alphas(
    const float* __restrict__ traces, const float* __restrict__ vtr,
    float* __restrict__ alphas) {
  int blk = blockIdx.x;
  const float* base;
  int n;
  if (blk < 16) { base = traces + blk * DKn * DKn; n = DKn * DKn; }
  else          { base = vtr + (blk - 16) * EDn * DKn; n = EDn * DKn; }
  float s = 0.f;
  for (int i = threadIdx.x; i < n; i += 256) { float v = base[i]; s += v * v; }
  __shared__ float red[256];
  red[threadIdx.x] = s;
  __syncthreads();
  for (int off = 128; off > 0; off >>= 1) {
    if (threadIdx.x < off) red[threadIdx.x] += red[threadIdx.x + off];
    __syncthreads();
  }
  if (threadIdx.x == 0) alphas[blk] = 0.05f / (1.f + sqrtf(red[0]));
}

// ---------------- prepass: W^T -> bf16  (Wt[n][k] = W[k][n]) ----------------
__global__ __launch_bounds__(256) void k_trW(
    const float* __restrict__ w0, const float* __restrict__ w1,
    const float* __restrict__ w2, const float* __restrict__ w3,
    unsigned short* __restrict__ dst) {
  int z = blockIdx.z;
  const float* src = (z == 0) ? w0 : ((z == 1) ? w1 : ((z == 2) ? w2 : w3));
  unsigned short* d = dst + (size_t)z * Dn * Dn;
  __shared__ unsigned short Tl[64][72];
  int tid = threadIdx.x;
  int k0 = blockIdx.y * 64, n0 = blockIdx.x * 64;
#pragma unroll
  for (int i = 0; i < 4; ++i) {
    int q = tid + 256 * i;
    int kr = q >> 4, c4 = q & 15;
    float4 v = *(const float4*)&src[(size_t)(k0 + kr) * Dn + n0 + 4 * c4];
    ushort4 u;
    u.x = f2b(v.x); u.y = f2b(v.y); u.z = f2b(v.z); u.w = f2b(v.w);
    *(ushort4*)&Tl[kr][4 * c4] = u;
  }
  __syncthreads();
#pragma unroll
  for (int i = 0; i < 4; ++i) {
    int q = tid + 256 * i;
    int nr = q >> 4, c4 = q & 15;
    ushort4 u;
    u.x = Tl[4 * c4 + 0][nr]; u.y = Tl[4 * c4 + 1][nr];
    u.z = Tl[4 * c4 + 2][nr]; u.w = Tl[4 * c4 + 3][nr];
    *(ushort4*)&d[(size_t)(n0 + nr) * Dn + k0 + 4 * c4] = u;
  }
}

// ---------------- prepass: Mt[h][e][k] = 0.125*(I + alpha_h*T_h)[k][e] -----
__global__ __launch_bounds__(256) void k_mkM(const float* __restrict__ tr,
                                             const float* __restrict__ alph,
                                             unsigned short* __restrict__ Mt) {
  int h = blockIdx.x;
  float a = alph[h] * 0.125f;
  const float* th = tr + (size_t)h * DKn * DKn;
  unsigned short* mh = Mt + (size_t)h * DKn * DKn;
  for (int i = threadIdx.x; i < DKn * DKn; i += 256) {
    int e = i >> 6, k = i & 63;
    float v = a * th[(size_t)k * DKn + e] + ((e == k) ? 0.125f : 0.f);
    mh[i] = f2b(v);
  }
}

// ---------------- prepass: Wexp[64][256] -> WexpT[256][64] bf16 ------------
__global__ __launch_bounds__(256) void k_trE(const float* __restrict__ Wexp,
                                             unsigned short* __restrict__ WexpT) {
  int e0 = blockIdx.x * 64;
  __shared__ unsigned short Tl[64][72];
  int tid = threadIdx.x;
#pragma unroll
  for (int i = 0; i < 4; ++i) {
    int q = tid + 256 * i;
    int dr = q >> 4, c4 = q & 15;
    float4 v = *(const float4*)&Wexp[(size_t)dr * EDn + e0 + 4 * c4];
    ushort4 u;
    u.x = f2b(v.x); u.y = f2b(v.y); u.z = f2b(v.z); u.w = f2b(v.w);
    *(ushort4*)&Tl[dr][4 * c4] = u;
  }
  __syncthreads();
#pragma unroll
  for (int i = 0; i < 4; ++i) {
    int q = tid + 256 * i;
    int er = q >> 4, c4 = q & 15;
    ushort4 u;
    u.x = Tl[4 * c4 + 0][er]; u.y = Tl[4 * c4 + 1][er];
    u.z = Tl[4 * c4 + 2][er]; u.w = Tl[4 * c4 + 3][er];
    *(ushort4*)&WexpT[(size_t)(e0 + er) * DKn + 4 * c4] = u;
  }
}

// ---------------- prepass: vtr[h][256][64] -> VTt[h][64][256] bf16 ---------
__global__ __launch_bounds__(256) void k_trVT(const float* __restrict__ vtr,
                                              unsigned short* __restrict__ VTt) {
  int e0 = blockIdx.x * 64;
  int h = blockIdx.y;
  const float* src = vtr + (size_t)h * EDn * DKn;
  unsigned short* dst = VTt + (size_t)h * DKn * EDn;
  __shared__ unsigned short Tl[64][72];
  int tid = threadIdx.x;
#pragma unroll
  for (int i = 0; i < 4; ++i) {
    int q = tid + 256 * i;
    int er = q >> 4, c4 = q & 15;
    float4 v = *(const float4*)&src[(size_t)(e0 + er) * DKn + 4 * c4];
    ushort4 u;
    u.x = f2b(v.x); u.y = f2b(v.y); u.z = f2b(v.z); u.w = f2b(v.w);
    *(ushort4*)&Tl[er][4 * c4] = u;
  }
  __syncthreads();
#pragma unroll
  for (int i = 0; i < 4; ++i) {
    int q = tid + 256 * i;
    int dr = q >> 4, c4 = q & 15;
    ushort4 u;
    u.x = Tl[4 * c4 + 0][dr]; u.y = Tl[4 * c4 + 1][dr];
    u.z = Tl[4 * c4 + 2][dr]; u.w = Tl[4 * c4 + 3][dr];
    *(ushort4*)&dst[(size_t)dr * EDn + e0 + 4 * c4] = u;
  }
}

// ---------------- prepass: x fp32 -> bf16 ----------------------------------
__global__ __launch_bounds__(256) void k_xb(const float* __restrict__ x,
                                            unsigned short* __restrict__ xb) {
  size_t i = ((size_t)blockIdx.x * 256 + threadIdx.x) * 4;
  float4 v = *(const float4*)&x[i];
  ushort4 u;
  u.x = f2b(v.x); u.y = f2b(v.y); u.z = f2b(v.z); u.w = f2b(v.w);
  *(ushort4*)&xb[i] = u;
}

// ---------------- MFMA GEMM: 128x128 tile, BK=32, 4 waves 2x2 --------------
// MODE 0: A bf16, 3 outputs bf16 remapped (b,h,s,dk). MODE 1: A fp32, C fp32.
template <int MODE>
__global__ __launch_bounds__(256) void k_gemm(
    const unsigned short* __restrict__ Ab, const float* __restrict__ Af,
    const unsigned short* __restrict__ BtBase, unsigned short* __restrict__ Qb,
    unsigned short* __restrict__ Kb, unsigned short* __restrict__ Vb,
    float* __restrict__ Cout) {
  const int z = (MODE == 0) ? blockIdx.z : 0;
  const unsigned short* Bt = BtBase + (size_t)z * Dn * Dn;
  unsigned short* Cb =
      (MODE == 0) ? ((z == 0) ? Qb : ((z == 1) ? Kb : Vb)) : nullptr;
  __shared__ unsigned short As[128][40];
  __shared__ unsigned short Bs[128][40];
  const int tid = threadIdx.x;
  const int w = tid >> 6, lane = tid & 63, qd = lane >> 4, cc = lane & 15;
  const int m0 = blockIdx.y * 128, n0 = blockIdx.x * 128;
  const int mW = 64 * (w >> 1), nW = 64 * (w & 1);
  fvec4 acc[4][4];
#pragma unroll
  for (int i = 0; i < 4; ++i)
#pragma unroll
    for (int j = 0; j < 4; ++j) acc[i][j] = (fvec4){0.f, 0.f, 0.f, 0.f};

  for (int k0 = 0; k0 < Dn; k0 += 32) {
    if (MODE == 0) {
#pragma unroll
      for (int i = 0; i < 2; ++i) {
        int q = tid + 256 * i;
        int row = q >> 2, c8 = q & 3;
        *(uint4*)&As[row][8 * c8] =
            *(const uint4*)&Ab[(size_t)(m0 + row) * Dn + k0 + 8 * c8];
      }
    } else {
#pragma unroll
      for (int i = 0; i < 4; ++i) {
        int q = tid + 256 * i;
        int row = q >> 3, c4 = q & 7;
        float4 v = *(const float4*)&Af[(size_t)(m0 + row) * Dn + k0 + 4 * c4];
        ushort4 u;
        u.x = f2b(v.x); u.y = f2b(v.y); u.z = f2b(v.z); u.w = f2b(v.w);
        *(ushort4*)&As[row][4 * c4] = u;
      }
    }
#pragma unroll
    for (int i = 0; i < 2; ++i) {
      int q = tid + 256 * i;
      int row = q >> 2, c8 = q & 3;
      *(uint4*)&Bs[row][8 * c8] =
          *(const uint4*)&Bt[(size_t)(n0 + row) * Dn + k0 + 8 * c8];
    }
    __syncthreads();
    bvec8 af[4], bf[4];
#pragma unroll
    for (int i = 0; i < 4; ++i) {
      af[i] = *(const bvec8*)&As[mW + 16 * i + cc][8 * qd];
      bf[i] = *(const bvec8*)&Bs[nW + 16 * i + cc][8 * qd];
    }
#pragma unroll
    for (int i = 0; i < 4; ++i)
#pragma unroll
      for (int j = 0; j < 4; ++j) acc[i][j] = MFMA(af[i], bf[j], acc[i][j]);
    __syncthreads();
  }
#pragma unroll
  for (int i = 0; i < 4; ++i)
#pragma unroll
    for (int j = 0; j < 4; ++j)
#pragma unroll
      for (int r = 0; r < 4; ++r) {
        int row = m0 + mW + 16 * i + 4 * qd + r;
        int col = n0 + nW + 16 * j + cc;
        if (MODE == 0) {
          int b = row >> 11, s = row & 2047, h = col >> 6, dk = col & 63;
          Cb[(((size_t)(b * Hn + h)) * Sn + s) * DKn + dk] = f2b(acc[i][j][r]);
        } else {
          Cout[(size_t)row * Dn + col] = acc[i][j][r];
        }
      }
}

// ---------------- V transpose: Vb[bh][s][d] -> Vt[bh][d][s] ----------------
__global__ __launch_bounds__(256) void k_vtrans(
    const unsigned short* __restrict__ Vb, unsigned short* __restrict__ Vt) {
  int bh = blockIdx.x, st = blockIdx.y;
  __shared__ unsigned short Tl[64][72];
  int tid = threadIdx.x;
#pragma unroll
  for (int i = 0; i < 4; ++i) {
    int q = tid + 256 * i;
    int sr = q >> 4, c4 = q & 15;
    *(ushort4*)&Tl[sr][4 * c4] =
        *(const ushort4*)&Vb[((size_t)bh * Sn + st * 64 + sr) * DKn + 4 * c4];
  }
  __syncthreads();
#pragma unroll
  for (int i = 0; i < 4; ++i) {
    int q = tid + 256 * i;
    int dr = q >> 4, c4 = q & 15;
    ushort4 u;
    u.x = Tl[4 * c4 + 0][dr]; u.y = Tl[4 * c4 + 1][dr];
    u.z = Tl[4 * c4 + 2][dr]; u.w = Tl[4 * c4 + 3][dr];
    *(ushort4*)&Vt[((size_t)bh * DKn + dr) * Sn + st * 64 + 4 * c4] = u;
  }
}

// ---------------- pattern separation: LDS-resident tables, swizzled --------
// grid (tile=16, bh=32): 128 rows/block, 4 waves x 2 row-groups of 16.
// LDS: Wl 32K + Vl 32K + Ps(half-K) 16K = 80K -> 2 blocks/CU.
__global__ __launch_bounds__(256, 2) void k_pattsep(
    const unsigned short* __restrict__ Qb,
    const unsigned short* __restrict__ WexpT,  // [256][64] bf16
    const unsigned short* __restrict__ VTt,    // [16][64][256] bf16
    const float* __restrict__ alphas, float* __restrict__ AT) {
  __shared__ uint4 Wl4[2048];    // WexpT swizzled: (e,c8) at e*8 + (c^(e&7))
  __shared__ uint4 Vl4[2048];    // VTt_h swizzled: (d,c32) at d*32 + (c^(d&7))
  __shared__ uint4 Ps4[4][256];  // per-wave P k-half [16][128]sw
  const int tile = blockIdx.x, bh = blockIdx.y;
  const int b = bh >> 4, h = bh & 15;
  const int tid = threadIdx.x;
  const int w = tid >> 6, lane = tid & 63, qd = lane >> 4, cc = lane & 15;
  const float avt = alphas[16 + h];

  const uint4* wsrc = (const uint4*)WexpT;
  const uint4* vsrc = (const uint4*)(VTt + (size_t)h * DKn * EDn);
  for (int i = tid; i < 2048; i += 256) {
    int e = i >> 3, c = i & 7;
    Wl4[e * 8 + (c ^ (e & 7))] = wsrc[i];
    int d = i >> 5, c2 = i & 31;
    Vl4[d * 32 + (c2 ^ (d & 7))] = vsrc[i];
  }
  __syncthreads();

  const unsigned short* Wls = (const unsigned short*)Wl4;
  const unsigned short* Vls = (const unsigned short*)Vl4;
  unsigned short* Pw = (unsigned short*)Ps4[w];

  for (int rg = 0; rg < 2; ++rg) {
    const int s0 = tile * 128 + w * 32 + rg * 16;
    // A-frags: Qprev rows (s0+cc-1); zero row for s==0
    bvec8 aq0 = {}, aq1 = {};
    const int srow = s0 + cc;
    if (srow > 0) {
      const unsigned short* qp = Qb + ((size_t)bh * Sn + srow - 1) * DKn;
      aq0 = *(const bvec8*)&qp[8 * qd];
      aq1 = *(const bvec8*)&qp[32 + 8 * qd];
    }
    // expand: E[j] covers cols 16j+cc, rows 4qd+r
    fvec4 E[16];
#pragma unroll
    for (int j = 0; j < 16; ++j) {
      const int e = 16 * j + cc;
      const unsigned short* wr = Wls + e * 64;
      bvec8 b0 = *(const bvec8*)&wr[8 * (qd ^ (e & 7))];
      bvec8 b1 = *(const bvec8*)&wr[8 * ((4 + qd) ^ (e & 7))];
      fvec4 z = {0.f, 0.f, 0.f, 0.f};
      z = MFMA(aq0, b0, z);
      E[j] = MFMA(aq1, b1, z);
    }
#pragma unroll
    for (int j = 0; j < 16; ++j)
#pragma unroll
      for (int r = 0; r < 4; ++r) E[j][r] = fmaxf(E[j][r], 0.f);

    // per-row 32nd-largest via bit binary search; 4 rows (quads) in parallel
    float thr[4];
#pragma unroll
    for (int r = 0; r < 4; ++r) {
      unsigned cur = 0u;
      bool done = false;
      for (int bit = 30; bit >= 0; --bit) {
        unsigned cand = cur | (1u << bit);
        float t = __uint_as_float(cand);
        int cnt = 0;
#pragma unroll
        for (int j = 0; j < 16; ++j) cnt += (E[j][r] >= t) ? 1 : 0;
        cnt += __shfl_xor(cnt, 1);
        cnt += __shfl_xor(cnt, 2);
        cnt += __shfl_xor(cnt, 4);
        cnt += __shfl_xor(cnt, 8);
        if (!done && cnt >= 32) {
          cur = cand;
          if (cnt == 32) done = true;
        }
        if (__all(done)) break;
      }
      thr[r] = __uint_as_float(cur);
    }

    fvec4 acc2[4];
#pragma unroll
    for (int j2 = 0; j2 < 4; ++j2) acc2[j2] = (fvec4){0.f, 0.f, 0.f, 0.f};

#pragma unroll
    for (int half = 0; half < 2; ++half) {
      // write this k-half of sparse P into Pw ([16][128] swizzled)
#pragma unroll
      for (int j = 0; j < 8; ++j) {
        const int jj = j + 8 * half;
#pragma unroll
        for (int r = 0; r < 4; ++r) {
          float v = E[jj][r];
          bool sel = (v >= thr[r]) && (v > 0.f);
          int row = 4 * qd + r;
          int s = 16 * j + cc;
          int ch = (s >> 3) ^ (row & 7);
          Pw[row * 128 + ch * 8 + (s & 7)] = sel ? f2b(v) : (unsigned short)0;
        }
      }
      // PV for this half: contraction over e in [128*half, 128*half+128)
#pragma unroll
      for (int j2 = 0; j2 < 4; ++j2) {
        const int d = 16 * j2 + cc;
        const unsigned short* vr = Vls + d * 256;
#pragma unroll
        for (int c = 0; c < 4; ++c) {
          int cg = 4 * (c + 4 * half) + qd;  // global 16B-chunk in V row
          bvec8 bv = *(const bvec8*)&vr[8 * (cg ^ (d & 7))];
          int ca = 4 * c + qd;               // chunk within Ps half
          bvec8 ap = *(const bvec8*)&Pw[cc * 128 + 8 * (ca ^ (cc & 7))];
          acc2[j2] = MFMA(ap, bv, acc2[j2]);
        }
      }
    }
#pragma unroll
    for (int j2 = 0; j2 < 4; ++j2)
#pragma unroll
      for (int r = 0; r < 4; ++r) {
        int row = s0 + 4 * qd + r;
        AT[((size_t)(b * Sn + row)) * Dn + h * DKn + 16 * j2 + cc] =
            avt * acc2[j2][r];
      }
  }
}

// ---------------- flash attention + fused fold, fixed-max softmax ----------
__global__ __launch_bounds__(256) void k_attn(
    const unsigned short* __restrict__ Qb, const unsigned short* __restrict__ Kb,
    const unsigned short* __restrict__ Vt, const unsigned short* __restrict__ Mt,
    float* __restrict__ AT) {
  __shared__ unsigned short Kd[64][72];
  __shared__ unsigned short Vl[64][72];
  __shared__ unsigned short Ps[4][16][72];
  const int bh = blockIdx.x, qt = blockIdx.y;
  const int b = bh >> 4, h = bh & 15;
  const int tid = threadIdx.x;
  const int w = tid >> 6, lane = tid & 63, qd = lane >> 4, cc = lane & 15;
  const float L2E = 1.4426950408889634f;
  const float NB = 23.083120654223414f;  // 16*log2(e)

  // fused fold: Q' = Qraw @ M, M = 0.125*(I + alpha*T), via Mt[h][e][k]
  const unsigned short* qg = Qb + ((size_t)bh * Sn + qt * 64 + w * 16) * DKn;
  bvec8 a0 = *(const bvec8*)&qg[cc * DKn + 8 * qd];
  bvec8 a1 = *(const bvec8*)&qg[cc * DKn + 32 + 8 * qd];
  const unsigned short* mh = Mt + (size_t)h * DKn * DKn;
  unsigned short(*Qd)[72] = &Kd[16 * w];  // reuse Kd before first barrier
#pragma unroll
  for (int j = 0; j < 4; ++j) {
    bvec8 b0 = *(const bvec8*)&mh[(size_t)(16 * j + cc) * DKn + 8 * qd];
    bvec8 b1 = *(const bvec8*)&mh[(size_t)(16 * j + cc) * DKn + 32 + 8 * qd];
    fvec4 z = {0.f, 0.f, 0.f, 0.f};
    z = MFMA(a0, b0, z);
    z = MFMA(a1, b1, z);
#pragma unroll
    for (int r = 0; r < 4; ++r) Qd[4 * qd + r][16 * j + cc] = f2b(z[r]);
  }
  bvec8 aq0 = *(const bvec8*)&Qd[cc][8 * qd];
  bvec8 aq1 = *(const bvec8*)&Qd[cc][32 + 8 * qd];

  float l_i[4] = {0.f, 0.f, 0.f, 0.f};
  fvec4 O[4];
#pragma unroll
  for (int j = 0; j < 4; ++j) O[j] = (fvec4){0.f, 0.f, 0.f, 0.f};

  for (int kt = 0; kt < Sn / 64; ++kt) {
    __syncthreads();
#pragma unroll
    for (int i = 0; i < 2; ++i) {
      int q = tid + 256 * i;
      int r = q >> 3, c8 = q & 7;
      *(uint4*)&Kd[r][8 * c8] =
          *(const uint4*)&Kb[((size_t)bh * Sn + kt * 64 + r) * DKn + 8 * c8];
      *(uint4*)&Vl[r][8 * c8] =
          *(const uint4*)&Vt[((size_t)bh * DKn + r) * Sn + kt * 64 + 8 * c8];
    }
    __syncthreads();
    fvec4 sc[4];
#pragma unroll
    for (int j = 0; j < 4; ++j) {
      bvec8 b0 = *(const bvec8*)&Kd[16 * j + cc][8 * qd];
      bvec8 b1 = *(const bvec8*)&Kd[16 * j + cc][32 + 8 * qd];
      fvec4 z = {0.f, 0.f, 0.f, 0.f};
      z = MFMA(aq0, b0, z);
      sc[j] = MFMA(aq1, b1, z);
    }
    // fixed-offset softmax: p = e^(s-16); common factor cancels in O/l
#pragma unroll
    for (int j = 0; j < 4; ++j)
#pragma unroll
      for (int r = 0; r < 4; ++r) {
        float p = exp2f(fmaf(sc[j][r], L2E, -NB));
        l_i[r] += p;
        Ps[w][4 * qd + r][16 * j + cc] = f2b(p);
      }
    bvec8 ap0 = *(const bvec8*)&Ps[w][cc][8 * qd];
    bvec8 ap1 = *(const bvec8*)&Ps[w][cc][32 + 8 * qd];
#pragma unroll
    for (int j = 0; j < 4; ++j) {
      bvec8 v0 = *(const bvec8*)&Vl[16 * j + cc][8 * qd];
      bvec8 v1 = *(const bvec8*)&Vl[16 * j + cc][32 + 8 * qd];
      O[j] = MFMA(ap0, v0, O[j]);
      O[j] = MFMA(ap1, v1, O[j]);
    }
  }
#pragma unroll
  for (int r = 0; r < 4; ++r) {
    l_i[r] += __shfl_xor(l_i[r], 1);
    l_i[r] += __shfl_xor(l_i[r], 2);
    l_i[r] += __shfl_xor(l_i[r], 4);
    l_i[r] += __shfl_xor(l_i[r], 8);
  }
  float inv[4];
#pragma unroll
  for (int r = 0; r < 4; ++r) inv[r] = 1.f / l_i[r];
#pragma unroll
  for (int j = 0; j < 4; ++j)
#pragma unroll
    for (int r = 0; r < 4; ++r) {
      int row = qt * 64 + w * 16 + 4 * qd + r;
      float* p = AT + ((size_t)(b * Sn + row)) * Dn + h * DKn + 16 * j + cc;
      *p += O[j][r] * inv[r];
    }
}

// ---------------- launch ----------------
extern "C" void kernel_launch(void* const* d_in, const int* in_sizes, int n_in,
                              void* d_out, int out_size, void* d_ws,
                              size_t ws_size, hipStream_t stream) {
  const float* x = (const float*)d_in[0];
  const float* Wq = (const float*)d_in[1];
  const float* Wk = (const float*)d_in[2];
  const float* Wv = (const float*)d_in[3];
  const float* Wo = (const float*)d_in[4];
  const float* traces = (const float*)d_in[5];
  const float* vtr = (const float*)d_in[6];
  const float* Wexp = (const float*)d_in[7];

  const size_t NQ = (size_t)Bn * Hn * Sn * DKn;  // 4,194,304
  unsigned short* Qb = (unsigned short*)d_ws;
  unsigned short* Kb = Qb + NQ;
  unsigned short* Vb = Kb + NQ;
  unsigned short* Vt = Vb + NQ;
  unsigned short* Wt = Vt + NQ;                // 4 x D*D bf16 = NQ shorts
  unsigned short* Mt = Wt + NQ;                // 16*64*64 = 65536
  unsigned short* WexpT = Mt + 65536;          // 256*64 = 16384
  unsigned short* VTt = WexpT + 16384;         // 16*64*256 = 262144
  float* alph = (float*)(VTt + 262144);        // 32 floats
  float* AT = alph + 32;                       // (B,S,D) fp32, 16MB
  unsigned short* xb = (unsigned short*)AT;    // aliased: dead before pattsep

  k_alphas<<<32, 256, 0, stream>>>(traces, vtr, alph);
  k_trW<<<dim3(16, 16, 4), 256, 0, stream>>>(Wq, Wk, Wv, Wo, Wt);
  k_mkM<<<16, 256, 0, stream>>>(traces, alph, Mt);
  k_trE<<<4, 256, 0, stream>>>(Wexp, WexpT);
  k_trVT<<<dim3(4, 16), 256, 0, stream>>>(vtr, VTt);
  k_xb<<<4096, 256, 0, stream>>>(x, xb);
  k_gemm<0><<<dim3(8, 32, 3), 256, 0, stream>>>(xb, nullptr, Wt, Qb, Kb, Vb,
                                                nullptr);
  k_vtrans<<<dim3(32, 32), 256, 0, stream>>>(Vb, Vt);
  k_pattsep<<<dim3(16, 32), 256, 0, stream>>>(Qb, WexpT, VTt, alph, AT);
  k_attn<<<dim3(32, 32), 256, 0, stream>>>(Qb, Kb, Vt, Mt, AT);
  k_gemm<1><<<dim3(8, 32, 1), 256, 0, stream>>>(
      nullptr, AT, Wt + 3 * (size_t)Dn * Dn, nullptr, nullptr, nullptr,
      (float*)d_out);
}

// Round 6
// 324.170 us; speedup vs baseline: 4.1427x; 1.0444x over previous
//
#include <hip/hip_runtime.h>
#include <stdint.h>

#define Bn 2
#define Sn 2048
#define Dn 1024
#define Hn 16
#define DKn 64
#define EDn 256

typedef __attribute__((ext_vector_type(8))) short bvec8;   // 8 bf16 (4 VGPR)
typedef __attribute__((ext_vector_type(4))) float fvec4;   // 4 fp32 acc

#define MFMA(a, b, c) __builtin_amdgcn_mfma_f32_16x16x32_bf16(a, b, c, 0, 0, 0)

__device__ __forceinline__ float b2f(unsigned short u) {
  return __uint_as_float(((unsigned)u) << 16);
}
__device__ __forceinline__ unsigned short f2b(float x) {
  unsigned u = __float_as_uint(x);
  u += 0x7fffu + ((u >> 16) & 1u);
  return (unsigned short)(u >> 16);
}
// async global->LDS, 16B/lane; LDS dest is wave-uniform base + lane*16
__device__ __forceinline__ void g2l(const unsigned short* g, unsigned short* l) {
  __builtin_amdgcn_global_load_lds(
      (const __attribute__((address_space(1))) void*)g,
      (__attribute__((address_space(3))) void*)l, 16, 0, 0);
}

// ---------------- alphas: 0.05/(1+||.||_F) ----------------
__global__ __launch_bounds__(256) void k_alphas(
    const float* __restrict__ traces, const float* __restrict__ vtr,
    float* __restrict__ alphas) {
  int blk = blockIdx.x;
  const float* base;
  int n;
  if (blk < 16) { base = traces + blk * DKn * DKn; n = DKn * DKn; }
  else          { base = vtr + (blk - 16) * EDn * DKn; n = EDn * DKn; }
  float s = 0.f;
  for (int i = threadIdx.x; i < n; i += 256) { float v = base[i]; s += v * v; }
  __shared__ float red[256];
  red[threadIdx.x] = s;
  __syncthreads();
  for (int off = 128; off > 0; off >>= 1) {
    if (threadIdx.x < off) red[threadIdx.x] += red[threadIdx.x + off];
    __syncthreads();
  }
  if (threadIdx.x == 0) alphas[blk] = 0.05f / (1.f + sqrtf(red[0]));
}

// ---------------- prepass: W^T -> bf16  (Wt[n][k] = W[k][n]) ----------------
__global__ __launch_bounds__(256) void k_trW(
    const float* __restrict__ w0, const float* __restrict__ w1,
    const float* __restrict__ w2, const float* __restrict__ w3,
    unsigned short* __restrict__ dst) {
  int z = blockIdx.z;
  const float* src = (z == 0) ? w0 : ((z == 1) ? w1 : ((z == 2) ? w2 : w3));
  unsigned short* d = dst + (size_t)z * Dn * Dn;
  __shared__ unsigned short Tl[64][72];
  int tid = threadIdx.x;
  int k0 = blockIdx.y * 64, n0 = blockIdx.x * 64;
#pragma unroll
  for (int i = 0; i < 4; ++i) {
    int q = tid + 256 * i;
    int kr = q >> 4, c4 = q & 15;
    float4 v = *(const float4*)&src[(size_t)(k0 + kr) * Dn + n0 + 4 * c4];
    ushort4 u;
    u.x = f2b(v.x); u.y = f2b(v.y); u.z = f2b(v.z); u.w = f2b(v.w);
    *(ushort4*)&Tl[kr][4 * c4] = u;
  }
  __syncthreads();
#pragma unroll
  for (int i = 0; i < 4; ++i) {
    int q = tid + 256 * i;
    int nr = q >> 4, c4 = q & 15;
    ushort4 u;
    u.x = Tl[4 * c4 + 0][nr]; u.y = Tl[4 * c4 + 1][nr];
    u.z = Tl[4 * c4 + 2][nr]; u.w = Tl[4 * c4 + 3][nr];
    *(ushort4*)&d[(size_t)(n0 + nr) * Dn + k0 + 4 * c4] = u;
  }
}

// ---------------- prepass: Mt[h][e][k] = 0.125*(I + alpha_h*T_h)[k][e] -----
__global__ __launch_bounds__(256) void k_mkM(const float* __restrict__ tr,
                                             const float* __restrict__ alph,
                                             unsigned short* __restrict__ Mt) {
  int h = blockIdx.x;
  float a = alph[h] * 0.125f;
  const float* th = tr + (size_t)h * DKn * DKn;
  unsigned short* mh = Mt + (size_t)h * DKn * DKn;
  for (int i = threadIdx.x; i < DKn * DKn; i += 256) {
    int e = i >> 6, k = i & 63;
    float v = a * th[(size_t)k * DKn + e] + ((e == k) ? 0.125f : 0.f);
    mh[i] = f2b(v);
  }
}

// ---------------- prepass: Wexp[64][256] -> WexpT[256][64] bf16 ------------
__global__ __launch_bounds__(256) void k_trE(const float* __restrict__ Wexp,
                                             unsigned short* __restrict__ WexpT) {
  int e0 = blockIdx.x * 64;
  __shared__ unsigned short Tl[64][72];
  int tid = threadIdx.x;
#pragma unroll
  for (int i = 0; i < 4; ++i) {
    int q = tid + 256 * i;
    int dr = q >> 4, c4 = q & 15;
    float4 v = *(const float4*)&Wexp[(size_t)dr * EDn + e0 + 4 * c4];
    ushort4 u;
    u.x = f2b(v.x); u.y = f2b(v.y); u.z = f2b(v.z); u.w = f2b(v.w);
    *(ushort4*)&Tl[dr][4 * c4] = u;
  }
  __syncthreads();
#pragma unroll
  for (int i = 0; i < 4; ++i) {
    int q = tid + 256 * i;
    int er = q >> 4, c4 = q & 15;
    ushort4 u;
    u.x = Tl[4 * c4 + 0][er]; u.y = Tl[4 * c4 + 1][er];
    u.z = Tl[4 * c4 + 2][er]; u.w = Tl[4 * c4 + 3][er];
    *(ushort4*)&WexpT[(size_t)(e0 + er) * DKn + 4 * c4] = u;
  }
}

// ---------------- prepass: vtr[h][256][64] -> VTt[h][64][256] bf16 ---------
__global__ __launch_bounds__(256) void k_trVT(const float* __restrict__ vtr,
                                              unsigned short* __restrict__ VTt) {
  int e0 = blockIdx.x * 64;
  int h = blockIdx.y;
  const float* src = vtr + (size_t)h * EDn * DKn;
  unsigned short* dst = VTt + (size_t)h * DKn * EDn;
  __shared__ unsigned short Tl[64][72];
  int tid = threadIdx.x;
#pragma unroll
  for (int i = 0; i < 4; ++i) {
    int q = tid + 256 * i;
    int er = q >> 4, c4 = q & 15;
    float4 v = *(const float4*)&src[(size_t)(e0 + er) * DKn + 4 * c4];
    ushort4 u;
    u.x = f2b(v.x); u.y = f2b(v.y); u.z = f2b(v.z); u.w = f2b(v.w);
    *(ushort4*)&Tl[er][4 * c4] = u;
  }
  __syncthreads();
#pragma unroll
  for (int i = 0; i < 4; ++i) {
    int q = tid + 256 * i;
    int dr = q >> 4, c4 = q & 15;
    ushort4 u;
    u.x = Tl[4 * c4 + 0][dr]; u.y = Tl[4 * c4 + 1][dr];
    u.z = Tl[4 * c4 + 2][dr]; u.w = Tl[4 * c4 + 3][dr];
    *(ushort4*)&dst[(size_t)dr * EDn + e0 + 4 * c4] = u;
  }
}

// ---------------- prepass: x fp32 -> bf16 ----------------------------------
__global__ __launch_bounds__(256) void k_xb(const float* __restrict__ x,
                                            unsigned short* __restrict__ xb) {
  size_t i = ((size_t)blockIdx.x * 256 + threadIdx.x) * 4;
  float4 v = *(const float4*)&x[i];
  ushort4 u;
  u.x = f2b(v.x); u.y = f2b(v.y); u.z = f2b(v.z); u.w = f2b(v.w);
  *(ushort4*)&xb[i] = u;
}

// ---------------- MFMA GEMM: 128x128, BK=32, async LDS staging -------------
// LDS [128][32] unpadded, chunk-swizzled (global chunk c at LDS c^(row&3)).
// MODE 0: A bf16 async; z=0,1 -> Qb/Kb remapped (b,h,s,dk); z=2 -> Vt
//         transposed (bh,dk,s) packed ushort4. MODE 1: A fp32 manual, C fp32.
template <int MODE>
__global__ __launch_bounds__(256) void k_gemm(
    const unsigned short* __restrict__ Ab, const float* __restrict__ Af,
    const unsigned short* __restrict__ BtBase, unsigned short* __restrict__ Qb,
    unsigned short* __restrict__ Kb, unsigned short* __restrict__ VtOut,
    float* __restrict__ Cout) {
  const int z = (MODE == 0) ? blockIdx.z : 0;
  const unsigned short* Bt = BtBase + (size_t)z * Dn * Dn;
  __shared__ unsigned short As[128 * 32];
  __shared__ unsigned short Bs[128 * 32];
  const int tid = threadIdx.x;
  const int w = tid >> 6, lane = tid & 63, qd = lane >> 4, cc = lane & 15;
  const int m0 = blockIdx.y * 128, n0 = blockIdx.x * 128;
  const int mW = 64 * (w >> 1), nW = 64 * (w & 1);
  const int srow = lane >> 2;                       // 0..15
  const int schk = 8 * ((lane & 3) ^ (srow & 3));   // swizzled source chunk
  const int r0 = 32 * w + srow, r1 = r0 + 16;
  fvec4 acc[4][4];
#pragma unroll
  for (int i = 0; i < 4; ++i)
#pragma unroll
    for (int j = 0; j < 4; ++j) acc[i][j] = (fvec4){0.f, 0.f, 0.f, 0.f};

  for (int k0 = 0; k0 < Dn; k0 += 32) {
    if (MODE == 0) {
      g2l(&Ab[(size_t)(m0 + r0) * Dn + k0 + schk], &As[1024 * w]);
      g2l(&Ab[(size_t)(m0 + r1) * Dn + k0 + schk], &As[1024 * w + 512]);
    } else {
#pragma unroll
      for (int i = 0; i < 4; ++i) {
        int q = tid + 256 * i;
        int row = q >> 3, c4 = q & 7;
        float4 v = *(const float4*)&Af[(size_t)(m0 + row) * Dn + k0 + 4 * c4];
        ushort4 u;
        u.x = f2b(v.x); u.y = f2b(v.y); u.z = f2b(v.z); u.w = f2b(v.w);
        *(ushort4*)&As[row * 32 + 8 * ((c4 >> 1) ^ (row & 3)) + 4 * (c4 & 1)] =
            u;
      }
    }
    g2l(&Bt[(size_t)(n0 + r0) * Dn + k0 + schk], &Bs[1024 * w]);
    g2l(&Bt[(size_t)(n0 + r1) * Dn + k0 + schk], &Bs[1024 * w + 512]);
    __syncthreads();
    bvec8 af[4], bf[4];
#pragma unroll
    for (int i = 0; i < 4; ++i) {
      int ra = mW + 16 * i + cc;
      af[i] = *(const bvec8*)&As[ra * 32 + 8 * (qd ^ (ra & 3))];
      int rb = nW + 16 * i + cc;
      bf[i] = *(const bvec8*)&Bs[rb * 32 + 8 * (qd ^ (rb & 3))];
    }
#pragma unroll
    for (int i = 0; i < 4; ++i)
#pragma unroll
      for (int j = 0; j < 4; ++j) acc[i][j] = MFMA(af[i], bf[j], acc[i][j]);
    __syncthreads();
  }
#pragma unroll
  for (int i = 0; i < 4; ++i)
#pragma unroll
    for (int j = 0; j < 4; ++j) {
      int rowb = m0 + mW + 16 * i + 4 * qd;
      int col = n0 + nW + 16 * j + cc;
      if (MODE == 0) {
        int b = rowb >> 11, s = rowb & 2047;
        int h = col >> 6, dk = col & 63;
        if (z == 2) {
          ushort4 u;
          u.x = f2b(acc[i][j][0]); u.y = f2b(acc[i][j][1]);
          u.z = f2b(acc[i][j][2]); u.w = f2b(acc[i][j][3]);
          *(ushort4*)&VtOut[(((size_t)(b * Hn + h)) * DKn + dk) * Sn + s] = u;
        } else {
          unsigned short* Cb = (z == 0) ? Qb : Kb;
#pragma unroll
          for (int r = 0; r < 4; ++r)
            Cb[(((size_t)(b * Hn + h)) * Sn + s + r) * DKn + dk] =
                f2b(acc[i][j][r]);
        }
      } else {
#pragma unroll
        for (int r = 0; r < 4; ++r)
          Cout[(size_t)(rowb + r) * Dn + col] = acc[i][j][r];
      }
    }
}

// ---------------- pattern separation: LDS-resident tables, swizzled --------
__global__ __launch_bounds__(256, 2) void k_pattsep(
    const unsigned short* __restrict__ Qb,
    const unsigned short* __restrict__ WexpT,  // [256][64] bf16
    const unsigned short* __restrict__ VTt,    // [16][64][256] bf16
    const float* __restrict__ alphas, float* __restrict__ AT) {
  __shared__ uint4 Wl4[2048];
  __shared__ uint4 Vl4[2048];
  __shared__ uint4 Ps4[4][256];
  const int tile = blockIdx.x, bh = blockIdx.y;
  const int b = bh >> 4, h = bh & 15;
  const int tid = threadIdx.x;
  const int w = tid >> 6, lane = tid & 63, qd = lane >> 4, cc = lane & 15;
  const float avt = alphas[16 + h];

  const uint4* wsrc = (const uint4*)WexpT;
  const uint4* vsrc = (const uint4*)(VTt + (size_t)h * DKn * EDn);
  for (int i = tid; i < 2048; i += 256) {
    int e = i >> 3, c = i & 7;
    Wl4[e * 8 + (c ^ (e & 7))] = wsrc[i];
    int d = i >> 5, c2 = i & 31;
    Vl4[d * 32 + (c2 ^ (d & 7))] = vsrc[i];
  }
  __syncthreads();

  const unsigned short* Wls = (const unsigned short*)Wl4;
  const unsigned short* Vls = (const unsigned short*)Vl4;
  unsigned short* Pw = (unsigned short*)Ps4[w];

  for (int rg = 0; rg < 2; ++rg) {
    const int s0 = tile * 128 + w * 32 + rg * 16;
    bvec8 aq0 = {}, aq1 = {};
    const int srow = s0 + cc;
    if (srow > 0) {
      const unsigned short* qp = Qb + ((size_t)bh * Sn + srow - 1) * DKn;
      aq0 = *(const bvec8*)&qp[8 * qd];
      aq1 = *(const bvec8*)&qp[32 + 8 * qd];
    }
    fvec4 E[16];
#pragma unroll
    for (int j = 0; j < 16; ++j) {
      const int e = 16 * j + cc;
      const unsigned short* wr = Wls + e * 64;
      bvec8 b0 = *(const bvec8*)&wr[8 * (qd ^ (e & 7))];
      bvec8 b1 = *(const bvec8*)&wr[8 * ((4 + qd) ^ (e & 7))];
      fvec4 zv = {0.f, 0.f, 0.f, 0.f};
      zv = MFMA(aq0, b0, zv);
      E[j] = MFMA(aq1, b1, zv);
    }
#pragma unroll
    for (int j = 0; j < 16; ++j)
#pragma unroll
      for (int r = 0; r < 4; ++r) E[j][r] = fmaxf(E[j][r], 0.f);

    float thr[4];
#pragma unroll
    for (int r = 0; r < 4; ++r) {
      unsigned cur = 0u;
      bool done = false;
      for (int bit = 30; bit >= 0; --bit) {
        unsigned cand = cur | (1u << bit);
        float t = __uint_as_float(cand);
        int cnt = 0;
#pragma unroll
        for (int j = 0; j < 16; ++j) cnt += (E[j][r] >= t) ? 1 : 0;
        cnt += __shfl_xor(cnt, 1);
        cnt += __shfl_xor(cnt, 2);
        cnt += __shfl_xor(cnt, 4);
        cnt += __shfl_xor(cnt, 8);
        if (!done && cnt >= 32) {
          cur = cand;
          if (cnt == 32) done = true;
        }
        if (__all(done)) break;
      }
      thr[r] = __uint_as_float(cur);
    }

    fvec4 acc2[4];
#pragma unroll
    for (int j2 = 0; j2 < 4; ++j2) acc2[j2] = (fvec4){0.f, 0.f, 0.f, 0.f};

#pragma unroll
    for (int half = 0; half < 2; ++half) {
#pragma unroll
      for (int j = 0; j < 8; ++j) {
        const int jj = j + 8 * half;
#pragma unroll
        for (int r = 0; r < 4; ++r) {
          float v = E[jj][r];
          bool sel = (v >= thr[r]) && (v > 0.f);
          int row = 4 * qd + r;
          int s = 16 * j + cc;
          int ch = (s >> 3) ^ (row & 7);
          Pw[row * 128 + ch * 8 + (s & 7)] = sel ? f2b(v) : (unsigned short)0;
        }
      }
#pragma unroll
      for (int j2 = 0; j2 < 4; ++j2) {
        const int d = 16 * j2 + cc;
        const unsigned short* vr = Vls + d * 256;
#pragma unroll
        for (int c = 0; c < 4; ++c) {
          int cg = 4 * (c + 4 * half) + qd;
          bvec8 bv = *(const bvec8*)&vr[8 * (cg ^ (d & 7))];
          int ca = 4 * c + qd;
          bvec8 ap = *(const bvec8*)&Pw[cc * 128 + 8 * (ca ^ (cc & 7))];
          acc2[j2] = MFMA(ap, bv, acc2[j2]);
        }
      }
    }
#pragma unroll
    for (int j2 = 0; j2 < 4; ++j2)
#pragma unroll
      for (int r = 0; r < 4; ++r) {
        int row = s0 + 4 * qd + r;
        AT[((size_t)(b * Sn + row)) * Dn + h * DKn + 16 * j2 + cc] =
            avt * acc2[j2][r];
      }
  }
}

// ---------------- flash attention + fused fold, async staging, swizzled ----
__global__ __launch_bounds__(256) void k_attn(
    const unsigned short* __restrict__ Qb, const unsigned short* __restrict__ Kb,
    const unsigned short* __restrict__ Vt, const unsigned short* __restrict__ Mt,
    float* __restrict__ AT) {
  __shared__ unsigned short Kd[64 * 64];  // unpadded, chunk-swizzled c^(r&7)
  __shared__ unsigned short Vl[64 * 64];
  __shared__ unsigned short Ps[4][16][72];
  const int bh = blockIdx.x, qt = blockIdx.y;
  const int b = bh >> 4, h = bh & 15;
  const int tid = threadIdx.x;
  const int w = tid >> 6, lane = tid & 63, qd = lane >> 4, cc = lane & 15;
  const float L2E = 1.4426950408889634f;
  const float NB = 23.083120654223414f;  // 16*log2(e)

  // fused fold: Q' = Qraw @ M  (Kd reused as per-wave Qd before first barrier)
  const unsigned short* qg = Qb + ((size_t)bh * Sn + qt * 64 + w * 16) * DKn;
  bvec8 a0 = *(const bvec8*)&qg[cc * DKn + 8 * qd];
  bvec8 a1 = *(const bvec8*)&qg[cc * DKn + 32 + 8 * qd];
  const unsigned short* mh = Mt + (size_t)h * DKn * DKn;
#pragma unroll
  for (int j = 0; j < 4; ++j) {
    bvec8 b0 = *(const bvec8*)&mh[(size_t)(16 * j + cc) * DKn + 8 * qd];
    bvec8 b1 = *(const bvec8*)&mh[(size_t)(16 * j + cc) * DKn + 32 + 8 * qd];
    fvec4 zz = {0.f, 0.f, 0.f, 0.f};
    zz = MFMA(a0, b0, zz);
    zz = MFMA(a1, b1, zz);
#pragma unroll
    for (int r = 0; r < 4; ++r) {
      int qr = 4 * qd + r;
      Kd[(16 * w + qr) * 64 + 8 * ((2 * j + (cc >> 3)) ^ (qr & 7)) + (cc & 7)] =
          f2b(zz[r]);
    }
  }
  bvec8 aq0 = *(const bvec8*)&Kd[(16 * w + cc) * 64 + 8 * (qd ^ (cc & 7))];
  bvec8 aq1 =
      *(const bvec8*)&Kd[(16 * w + cc) * 64 + 8 * ((qd + 4) ^ (cc & 7))];

  float l_i[4] = {0.f, 0.f, 0.f, 0.f};
  fvec4 O[4];
#pragma unroll
  for (int j = 0; j < 4; ++j) O[j] = (fvec4){0.f, 0.f, 0.f, 0.f};

  const int vrow = lane >> 3;                       // 0..7
  const int vchk = 8 * ((lane & 7) ^ (vrow & 7));   // swizzled source chunk
  const unsigned short* kgb = Kb + (size_t)bh * Sn * DKn;
  const unsigned short* vgb = Vt + (size_t)bh * DKn * Sn;

  for (int kt = 0; kt < Sn / 64; ++kt) {
    __syncthreads();
    const unsigned short* kg = kgb + (size_t)kt * 64 * DKn;
    g2l(&kg[(size_t)(16 * w + vrow) * 64 + vchk], &Kd[1024 * w]);
    g2l(&kg[(size_t)(16 * w + 8 + vrow) * 64 + vchk], &Kd[1024 * w + 512]);
    g2l(&vgb[(size_t)(16 * w + vrow) * Sn + kt * 64 + vchk], &Vl[1024 * w]);
    g2l(&vgb[(size_t)(16 * w + 8 + vrow) * Sn + kt * 64 + vchk],
        &Vl[1024 * w + 512]);
    __syncthreads();
    fvec4 sc[4];
#pragma unroll
    for (int j = 0; j < 4; ++j) {
      int rk = 16 * j + cc;
      bvec8 b0 = *(const bvec8*)&Kd[rk * 64 + 8 * (qd ^ (cc & 7))];
      bvec8 b1 = *(const bvec8*)&Kd[rk * 64 + 8 * ((qd + 4) ^ (cc & 7))];
      fvec4 zz = {0.f, 0.f, 0.f, 0.f};
      zz = MFMA(aq0, b0, zz);
      sc[j] = MFMA(aq1, b1, zz);
    }
    // fixed-offset softmax: p = e^(s-16); common factor cancels in O/l
#pragma unroll
    for (int j = 0; j < 4; ++j)
#pragma unroll
      for (int r = 0; r < 4; ++r) {
        float p = exp2f(fmaf(sc[j][r], L2E, -NB));
        l_i[r] += p;
        Ps[w][4 * qd + r][16 * j + cc] = f2b(p);
      }
    bvec8 ap0 = *(const bvec8*)&Ps[w][cc][8 * qd];
    bvec8 ap1 = *(const bvec8*)&Ps[w][cc][32 + 8 * qd];
#pragma unroll
    for (int j = 0; j < 4; ++j) {
      int rv = 16 * j + cc;
      bvec8 v0 = *(const bvec8*)&Vl[rv * 64 + 8 * (qd ^ (cc & 7))];
      bvec8 v1 = *(const bvec8*)&Vl[rv * 64 + 8 * ((qd + 4) ^ (cc & 7))];
      O[j] = MFMA(ap0, v0, O[j]);
      O[j] = MFMA(ap1, v1, O[j]);
    }
  }
#pragma unroll
  for (int r = 0; r < 4; ++r) {
    l_i[r] += __shfl_xor(l_i[r], 1);
    l_i[r] += __shfl_xor(l_i[r], 2);
    l_i[r] += __shfl_xor(l_i[r], 4);
    l_i[r] += __shfl_xor(l_i[r], 8);
  }
  float inv[4];
#pragma unroll
  for (int r = 0; r < 4; ++r) inv[r] = 1.f / l_i[r];
#pragma unroll
  for (int j = 0; j < 4; ++j)
#pragma unroll
    for (int r = 0; r < 4; ++r) {
      int row = qt * 64 + w * 16 + 4 * qd + r;
      float* p = AT + ((size_t)(b * Sn + row)) * Dn + h * DKn + 16 * j + cc;
      *p += O[j][r] * inv[r];
    }
}

// ---------------- launch ----------------
extern "C" void kernel_launch(void* const* d_in, const int* in_sizes, int n_in,
                              void* d_out, int out_size, void* d_ws,
                              size_t ws_size, hipStream_t stream) {
  const float* x = (const float*)d_in[0];
  const float* Wq = (const float*)d_in[1];
  const float* Wk = (const float*)d_in[2];
  const float* Wv = (const float*)d_in[3];
  const float* Wo = (const float*)d_in[4];
  const float* traces = (const float*)d_in[5];
  const float* vtr = (const float*)d_in[6];
  const float* Wexp = (const float*)d_in[7];

  const size_t NQ = (size_t)Bn * Hn * Sn * DKn;  // 4,194,304
  unsigned short* Qb = (unsigned short*)d_ws;
  unsigned short* Kb = Qb + NQ;
  unsigned short* Vt = Kb + NQ;                // (bh, dk, s) bf16
  unsigned short* Wt = Vt + NQ;                // 4 x D*D bf16 = NQ shorts
  unsigned short* Mt = Wt + NQ;                // 16*64*64 = 65536
  unsigned short* WexpT = Mt + 65536;          // 256*64 = 16384
  unsigned short* VTt = WexpT + 16384;         // 16*64*256 = 262144
  float* alph = (float*)(VTt + 262144);        // 32 floats
  float* AT = alph + 32;                       // (B,S,D) fp32, 16MB
  unsigned short* xb = (unsigned short*)AT;    // aliased: dead before pattsep

  k_alphas<<<32, 256, 0, stream>>>(traces, vtr, alph);
  k_trW<<<dim3(16, 16, 4), 256, 0, stream>>>(Wq, Wk, Wv, Wo, Wt);
  k_mkM<<<16, 256, 0, stream>>>(traces, alph, Mt);
  k_trE<<<4, 256, 0, stream>>>(Wexp, WexpT);
  k_trVT<<<dim3(4, 16), 256, 0, stream>>>(vtr, VTt);
  k_xb<<<4096, 256, 0, stream>>>(x, xb);
  k_gemm<0><<<dim3(8, 32, 3), 256, 0, stream>>>(xb, nullptr, Wt, Qb, Kb, Vt,
                                                nullptr);
  k_pattsep<<<dim3(16, 32), 256, 0, stream>>>(Qb, WexpT, VTt, alph, AT);
  k_attn<<<dim3(32, 32), 256, 0, stream>>>(Qb, Kb, Vt, Mt, AT);
  k_gemm<1><<<dim3(8, 32, 1), 256, 0, stream>>>(
      nullptr, AT, Wt + 3 * (size_t)Dn * Dn, nullptr, nullptr, nullptr,
      (float*)d_out);
}

// Round 7
// 309.525 us; speedup vs baseline: 4.3387x; 1.0473x over previous
//
#include <hip/hip_runtime.h>
#include <stdint.h>

#define Bn 2
#define Sn 2048
#define Dn 1024
#define Hn 16
#define DKn 64
#define EDn 256

typedef __attribute__((ext_vector_type(8))) short bvec8;   // 8 bf16 (4 VGPR)
typedef __attribute__((ext_vector_type(4))) float fvec4;   // 4 fp32 acc

#define MFMA(a, b, c) __builtin_amdgcn_mfma_f32_16x16x32_bf16(a, b, c, 0, 0, 0)

__device__ __forceinline__ float b2f(unsigned short u) {
  return __uint_as_float(((unsigned)u) << 16);
}
__device__ __forceinline__ unsigned short f2b(float x) {
  unsigned u = __float_as_uint(x);
  u += 0x7fffu + ((u >> 16) & 1u);
  return (unsigned short)(u >> 16);
}
// async global->LDS, 16B/lane; LDS dest is wave-uniform base + lane*16
__device__ __forceinline__ void g2l(const unsigned short* g, unsigned short* l) {
  __builtin_amdgcn_global_load_lds(
      (const __attribute__((address_space(1))) void*)g,
      (__attribute__((address_space(3))) void*)l, 16, 0, 0);
}

// ---------------- alphas: 0.05/(1+||.||_F) ----------------
__global__ __launch_bounds__(256) void k_alphas(
    const float* __restrict__ traces, const float* __restrict__ vtr,
    float* __restrict__ alphas) {
  int blk = blockIdx.x;
  const float* base;
  int n;
  if (blk < 16) { base = traces + blk * DKn * DKn; n = DKn * DKn; }
  else          { base = vtr + (blk - 16) * EDn * DKn; n = EDn * DKn; }
  float s = 0.f;
  for (int i = threadIdx.x; i < n; i += 256) { float v = base[i]; s += v * v; }
  __shared__ float red[256];
  red[threadIdx.x] = s;
  __syncthreads();
  for (int off = 128; off > 0; off >>= 1) {
    if (threadIdx.x < off) red[threadIdx.x] += red[threadIdx.x + off];
    __syncthreads();
  }
  if (threadIdx.x == 0) alphas[blk] = 0.05f / (1.f + sqrtf(red[0]));
}

// ---------------- prepass: W^T -> bf16  (Wt[n][k] = W[k][n]) ----------------
__global__ __launch_bounds__(256) void k_trW(
    const float* __restrict__ w0, const float* __restrict__ w1,
    const float* __restrict__ w2, const float* __restrict__ w3,
    unsigned short* __restrict__ dst) {
  int z = blockIdx.z;
  const float* src = (z == 0) ? w0 : ((z == 1) ? w1 : ((z == 2) ? w2 : w3));
  unsigned short* d = dst + (size_t)z * Dn * Dn;
  __shared__ unsigned short Tl[64][72];
  int tid = threadIdx.x;
  int k0 = blockIdx.y * 64, n0 = blockIdx.x * 64;
#pragma unroll
  for (int i = 0; i < 4; ++i) {
    int q = tid + 256 * i;
    int kr = q >> 4, c4 = q & 15;
    float4 v = *(const float4*)&src[(size_t)(k0 + kr) * Dn + n0 + 4 * c4];
    ushort4 u;
    u.x = f2b(v.x); u.y = f2b(v.y); u.z = f2b(v.z); u.w = f2b(v.w);
    *(ushort4*)&Tl[kr][4 * c4] = u;
  }
  __syncthreads();
#pragma unroll
  for (int i = 0; i < 4; ++i) {
    int q = tid + 256 * i;
    int nr = q >> 4, c4 = q & 15;
    ushort4 u;
    u.x = Tl[4 * c4 + 0][nr]; u.y = Tl[4 * c4 + 1][nr];
    u.z = Tl[4 * c4 + 2][nr]; u.w = Tl[4 * c4 + 3][nr];
    *(ushort4*)&d[(size_t)(n0 + nr) * Dn + k0 + 4 * c4] = u;
  }
}

// ---------------- prepass: Mt[h][e][k] = 0.125*(I + alpha_h*T_h)[k][e] -----
__global__ __launch_bounds__(256) void k_mkM(const float* __restrict__ tr,
                                             const float* __restrict__ alph,
                                             unsigned short* __restrict__ Mt) {
  int h = blockIdx.x;
  float a = alph[h] * 0.125f;
  const float* th = tr + (size_t)h * DKn * DKn;
  unsigned short* mh = Mt + (size_t)h * DKn * DKn;
  for (int i = threadIdx.x; i < DKn * DKn; i += 256) {
    int e = i >> 6, k = i & 63;
    float v = a * th[(size_t)k * DKn + e] + ((e == k) ? 0.125f : 0.f);
    mh[i] = f2b(v);
  }
}

// ---------------- prepass: Wexp[64][256] -> WexpT[256][64] bf16 ------------
__global__ __launch_bounds__(256) void k_trE(const float* __restrict__ Wexp,
                                             unsigned short* __restrict__ WexpT) {
  int e0 = blockIdx.x * 64;
  __shared__ unsigned short Tl[64][72];
  int tid = threadIdx.x;
#pragma unroll
  for (int i = 0; i < 4; ++i) {
    int q = tid + 256 * i;
    int dr = q >> 4, c4 = q & 15;
    float4 v = *(const float4*)&Wexp[(size_t)dr * EDn + e0 + 4 * c4];
    ushort4 u;
    u.x = f2b(v.x); u.y = f2b(v.y); u.z = f2b(v.z); u.w = f2b(v.w);
    *(ushort4*)&Tl[dr][4 * c4] = u;
  }
  __syncthreads();
#pragma unroll
  for (int i = 0; i < 4; ++i) {
    int q = tid + 256 * i;
    int er = q >> 4, c4 = q & 15;
    ushort4 u;
    u.x = Tl[4 * c4 + 0][er]; u.y = Tl[4 * c4 + 1][er];
    u.z = Tl[4 * c4 + 2][er]; u.w = Tl[4 * c4 + 3][er];
    *(ushort4*)&WexpT[(size_t)(e0 + er) * DKn + 4 * c4] = u;
  }
}

// ---------------- prepass: vtr[h][256][64] -> VTt[h][64][256] bf16 ---------
__global__ __launch_bounds__(256) void k_trVT(const float* __restrict__ vtr,
                                              unsigned short* __restrict__ VTt) {
  int e0 = blockIdx.x * 64;
  int h = blockIdx.y;
  const float* src = vtr + (size_t)h * EDn * DKn;
  unsigned short* dst = VTt + (size_t)h * DKn * EDn;
  __shared__ unsigned short Tl[64][72];
  int tid = threadIdx.x;
#pragma unroll
  for (int i = 0; i < 4; ++i) {
    int q = tid + 256 * i;
    int er = q >> 4, c4 = q & 15;
    float4 v = *(const float4*)&src[(size_t)(e0 + er) * DKn + 4 * c4];
    ushort4 u;
    u.x = f2b(v.x); u.y = f2b(v.y); u.z = f2b(v.z); u.w = f2b(v.w);
    *(ushort4*)&Tl[er][4 * c4] = u;
  }
  __syncthreads();
#pragma unroll
  for (int i = 0; i < 4; ++i) {
    int q = tid + 256 * i;
    int dr = q >> 4, c4 = q & 15;
    ushort4 u;
    u.x = Tl[4 * c4 + 0][dr]; u.y = Tl[4 * c4 + 1][dr];
    u.z = Tl[4 * c4 + 2][dr]; u.w = Tl[4 * c4 + 3][dr];
    *(ushort4*)&dst[(size_t)dr * EDn + e0 + 4 * c4] = u;
  }
}

// ---------------- prepass: x fp32 -> bf16 ----------------------------------
__global__ __launch_bounds__(256) void k_xb(const float* __restrict__ x,
                                            unsigned short* __restrict__ xb) {
  size_t i = ((size_t)blockIdx.x * 256 + threadIdx.x) * 4;
  float4 v = *(const float4*)&x[i];
  ushort4 u;
  u.x = f2b(v.x); u.y = f2b(v.y); u.z = f2b(v.z); u.w = f2b(v.w);
  *(ushort4*)&xb[i] = u;
}

// ---------------- MFMA GEMM: 128x128, BK=32, async LDS staging -------------
template <int MODE>
__global__ __launch_bounds__(256) void k_gemm(
    const unsigned short* __restrict__ Ab, const float* __restrict__ Af,
    const unsigned short* __restrict__ BtBase, unsigned short* __restrict__ Qb,
    unsigned short* __restrict__ Kb, unsigned short* __restrict__ VtOut,
    float* __restrict__ Cout) {
  const int z = (MODE == 0) ? blockIdx.z : 0;
  const unsigned short* Bt = BtBase + (size_t)z * Dn * Dn;
  __shared__ unsigned short As[128 * 32];
  __shared__ unsigned short Bs[128 * 32];
  const int tid = threadIdx.x;
  const int w = tid >> 6, lane = tid & 63, qd = lane >> 4, cc = lane & 15;
  const int m0 = blockIdx.y * 128, n0 = blockIdx.x * 128;
  const int mW = 64 * (w >> 1), nW = 64 * (w & 1);
  const int srow = lane >> 2;                       // 0..15
  const int schk = 8 * ((lane & 3) ^ (srow & 3));   // swizzled source chunk
  const int r0 = 32 * w + srow, r1 = r0 + 16;
  fvec4 acc[4][4];
#pragma unroll
  for (int i = 0; i < 4; ++i)
#pragma unroll
    for (int j = 0; j < 4; ++j) acc[i][j] = (fvec4){0.f, 0.f, 0.f, 0.f};

  for (int k0 = 0; k0 < Dn; k0 += 32) {
    if (MODE == 0) {
      g2l(&Ab[(size_t)(m0 + r0) * Dn + k0 + schk], &As[1024 * w]);
      g2l(&Ab[(size_t)(m0 + r1) * Dn + k0 + schk], &As[1024 * w + 512]);
    } else {
#pragma unroll
      for (int i = 0; i < 4; ++i) {
        int q = tid + 256 * i;
        int row = q >> 3, c4 = q & 7;
        float4 v = *(const float4*)&Af[(size_t)(m0 + row) * Dn + k0 + 4 * c4];
        ushort4 u;
        u.x = f2b(v.x); u.y = f2b(v.y); u.z = f2b(v.z); u.w = f2b(v.w);
        *(ushort4*)&As[row * 32 + 8 * ((c4 >> 1) ^ (row & 3)) + 4 * (c4 & 1)] =
            u;
      }
    }
    g2l(&Bt[(size_t)(n0 + r0) * Dn + k0 + schk], &Bs[1024 * w]);
    g2l(&Bt[(size_t)(n0 + r1) * Dn + k0 + schk], &Bs[1024 * w + 512]);
    __syncthreads();
    bvec8 af[4], bf[4];
#pragma unroll
    for (int i = 0; i < 4; ++i) {
      int ra = mW + 16 * i + cc;
      af[i] = *(const bvec8*)&As[ra * 32 + 8 * (qd ^ (ra & 3))];
      int rb = nW + 16 * i + cc;
      bf[i] = *(const bvec8*)&Bs[rb * 32 + 8 * (qd ^ (rb & 3))];
    }
#pragma unroll
    for (int i = 0; i < 4; ++i)
#pragma unroll
      for (int j = 0; j < 4; ++j) acc[i][j] = MFMA(af[i], bf[j], acc[i][j]);
    __syncthreads();
  }
#pragma unroll
  for (int i = 0; i < 4; ++i)
#pragma unroll
    for (int j = 0; j < 4; ++j) {
      int rowb = m0 + mW + 16 * i + 4 * qd;
      int col = n0 + nW + 16 * j + cc;
      if (MODE == 0) {
        int b = rowb >> 11, s = rowb & 2047;
        int h = col >> 6, dk = col & 63;
        if (z == 2) {
          ushort4 u;
          u.x = f2b(acc[i][j][0]); u.y = f2b(acc[i][j][1]);
          u.z = f2b(acc[i][j][2]); u.w = f2b(acc[i][j][3]);
          *(ushort4*)&VtOut[(((size_t)(b * Hn + h)) * DKn + dk) * Sn + s] = u;
        } else {
          unsigned short* Cb = (z == 0) ? Qb : Kb;
#pragma unroll
          for (int r = 0; r < 4; ++r)
            Cb[(((size_t)(b * Hn + h)) * Sn + s + r) * DKn + dk] =
                f2b(acc[i][j][r]);
        }
      } else {
#pragma unroll
        for (int r = 0; r < 4; ++r)
          Cout[(size_t)(rowb + r) * Dn + col] = acc[i][j][r];
      }
    }
}

// ---------------- pattern separation: LDS-resident tables, swizzled --------
__global__ __launch_bounds__(256, 2) void k_pattsep(
    const unsigned short* __restrict__ Qb,
    const unsigned short* __restrict__ WexpT,  // [256][64] bf16
    const unsigned short* __restrict__ VTt,    // [16][64][256] bf16
    const float* __restrict__ alphas, float* __restrict__ AT) {
  __shared__ uint4 Wl4[2048];
  __shared__ uint4 Vl4[2048];
  __shared__ uint4 Ps4[4][256];
  const int tile = blockIdx.x, bh = blockIdx.y;
  const int b = bh >> 4, h = bh & 15;
  const int tid = threadIdx.x;
  const int w = tid >> 6, lane = tid & 63, qd = lane >> 4, cc = lane & 15;
  const float avt = alphas[16 + h];

  const uint4* wsrc = (const uint4*)WexpT;
  const uint4* vsrc = (const uint4*)(VTt + (size_t)h * DKn * EDn);
  for (int i = tid; i < 2048; i += 256) {
    int e = i >> 3, c = i & 7;
    Wl4[e * 8 + (c ^ (e & 7))] = wsrc[i];
    int d = i >> 5, c2 = i & 31;
    Vl4[d * 32 + (c2 ^ (d & 7))] = vsrc[i];
  }
  __syncthreads();

  const unsigned short* Wls = (const unsigned short*)Wl4;
  const unsigned short* Vls = (const unsigned short*)Vl4;
  unsigned short* Pw = (unsigned short*)Ps4[w];

  for (int rg = 0; rg < 2; ++rg) {
    const int s0 = tile * 128 + w * 32 + rg * 16;
    bvec8 aq0 = {}, aq1 = {};
    const int srow = s0 + cc;
    if (srow > 0) {
      const unsigned short* qp = Qb + ((size_t)bh * Sn + srow - 1) * DKn;
      aq0 = *(const bvec8*)&qp[8 * qd];
      aq1 = *(const bvec8*)&qp[32 + 8 * qd];
    }
    fvec4 E[16];
#pragma unroll
    for (int j = 0; j < 16; ++j) {
      const int e = 16 * j + cc;
      const unsigned short* wr = Wls + e * 64;
      bvec8 b0 = *(const bvec8*)&wr[8 * (qd ^ (e & 7))];
      bvec8 b1 = *(const bvec8*)&wr[8 * ((4 + qd) ^ (e & 7))];
      fvec4 zv = {0.f, 0.f, 0.f, 0.f};
      zv = MFMA(aq0, b0, zv);
      E[j] = MFMA(aq1, b1, zv);
    }
#pragma unroll
    for (int j = 0; j < 16; ++j)
#pragma unroll
      for (int r = 0; r < 4; ++r) E[j][r] = fmaxf(E[j][r], 0.f);

    float thr[4];
#pragma unroll
    for (int r = 0; r < 4; ++r) {
      unsigned cur = 0u;
      bool done = false;
      for (int bit = 30; bit >= 0; --bit) {
        unsigned cand = cur | (1u << bit);
        float t = __uint_as_float(cand);
        int cnt = 0;
#pragma unroll
        for (int j = 0; j < 16; ++j) cnt += (E[j][r] >= t) ? 1 : 0;
        cnt += __shfl_xor(cnt, 1);
        cnt += __shfl_xor(cnt, 2);
        cnt += __shfl_xor(cnt, 4);
        cnt += __shfl_xor(cnt, 8);
        if (!done && cnt >= 32) {
          cur = cand;
          if (cnt == 32) done = true;
        }
        if (__all(done)) break;
      }
      thr[r] = __uint_as_float(cur);
    }

    fvec4 acc2[4];
#pragma unroll
    for (int j2 = 0; j2 < 4; ++j2) acc2[j2] = (fvec4){0.f, 0.f, 0.f, 0.f};

#pragma unroll
    for (int half = 0; half < 2; ++half) {
#pragma unroll
      for (int j = 0; j < 8; ++j) {
        const int jj = j + 8 * half;
#pragma unroll
        for (int r = 0; r < 4; ++r) {
          float v = E[jj][r];
          bool sel = (v >= thr[r]) && (v > 0.f);
          int row = 4 * qd + r;
          int s = 16 * j + cc;
          int ch = (s >> 3) ^ (row & 7);
          Pw[row * 128 + ch * 8 + (s & 7)] = sel ? f2b(v) : (unsigned short)0;
        }
      }
#pragma unroll
      for (int j2 = 0; j2 < 4; ++j2) {
        const int d = 16 * j2 + cc;
        const unsigned short* vr = Vls + d * 256;
#pragma unroll
        for (int c = 0; c < 4; ++c) {
          int cg = 4 * (c + 4 * half) + qd;
          bvec8 bv = *(const bvec8*)&vr[8 * (cg ^ (d & 7))];
          int ca = 4 * c + qd;
          bvec8 ap = *(const bvec8*)&Pw[cc * 128 + 8 * (ca ^ (cc & 7))];
          acc2[j2] = MFMA(ap, bv, acc2[j2]);
        }
      }
    }
#pragma unroll
    for (int j2 = 0; j2 < 4; ++j2)
#pragma unroll
      for (int r = 0; r < 4; ++r) {
        int row = s0 + 4 * qd + r;
        AT[((size_t)(b * Sn + row)) * Dn + h * DKn + 16 * j2 + cc] =
            avt * acc2[j2][r];
      }
  }
}

// ---------------- flash attention + fused fold, S^T softmax ----------------
// QK computed transposed (MFMA(K,Q)): C col=q (lanes), row=k (quads) ->
// single l accumulator per lane, packed ds_write_b64 P stores.
__global__ __launch_bounds__(256) void k_attn(
    const unsigned short* __restrict__ Qb, const unsigned short* __restrict__ Kb,
    const unsigned short* __restrict__ Vt, const unsigned short* __restrict__ Mt,
    float* __restrict__ AT) {
  __shared__ unsigned short Kd[64 * 64];  // unpadded, chunk-swizzled c^(r&7)
  __shared__ unsigned short Vl[64 * 64];
  __shared__ unsigned short Ps[4][16][72];  // per-wave P, row-major [q][k]
  const int bh = blockIdx.x, qt = blockIdx.y;
  const int b = bh >> 4, h = bh & 15;
  const int tid = threadIdx.x;
  const int w = tid >> 6, lane = tid & 63, qd = lane >> 4, cc = lane & 15;
  const float L2E = 1.4426950408889634f;
  const float NB = 23.083120654223414f;  // 16*log2(e)

  // fused fold: Q' = Qraw @ M  (Kd reused as per-wave Qd before first barrier)
  const unsigned short* qg = Qb + ((size_t)bh * Sn + qt * 64 + w * 16) * DKn;
  bvec8 a0 = *(const bvec8*)&qg[cc * DKn + 8 * qd];
  bvec8 a1 = *(const bvec8*)&qg[cc * DKn + 32 + 8 * qd];
  const unsigned short* mh = Mt + (size_t)h * DKn * DKn;
#pragma unroll
  for (int j = 0; j < 4; ++j) {
    bvec8 b0 = *(const bvec8*)&mh[(size_t)(16 * j + cc) * DKn + 8 * qd];
    bvec8 b1 = *(const bvec8*)&mh[(size_t)(16 * j + cc) * DKn + 32 + 8 * qd];
    fvec4 zz = {0.f, 0.f, 0.f, 0.f};
    zz = MFMA(a0, b0, zz);
    zz = MFMA(a1, b1, zz);
#pragma unroll
    for (int r = 0; r < 4; ++r) {
      int qr = 4 * qd + r;
      Kd[(16 * w + qr) * 64 + 8 * ((2 * j + (cc >> 3)) ^ (qr & 7)) + (cc & 7)] =
          f2b(zz[r]);
    }
  }
  bvec8 aq0 = *(const bvec8*)&Kd[(16 * w + cc) * 64 + 8 * (qd ^ (cc & 7))];
  bvec8 aq1 =
      *(const bvec8*)&Kd[(16 * w + cc) * 64 + 8 * ((qd + 4) ^ (cc & 7))];

  float l_s = 0.f;  // softmax denominator for q = cc (this lane's column)
  fvec4 O[4];
#pragma unroll
  for (int j = 0; j < 4; ++j) O[j] = (fvec4){0.f, 0.f, 0.f, 0.f};

  const int vrow = lane >> 3;                       // 0..7
  const int vchk = 8 * ((lane & 7) ^ (vrow & 7));   // swizzled source chunk
  const unsigned short* kgb = Kb + (size_t)bh * Sn * DKn;
  const unsigned short* vgb = Vt + (size_t)bh * DKn * Sn;

  for (int kt = 0; kt < Sn / 64; ++kt) {
    __syncthreads();
    const unsigned short* kg = kgb + (size_t)kt * 64 * DKn;
    g2l(&kg[(size_t)(16 * w + vrow) * 64 + vchk], &Kd[1024 * w]);
    g2l(&kg[(size_t)(16 * w + 8 + vrow) * 64 + vchk], &Kd[1024 * w + 512]);
    g2l(&vgb[(size_t)(16 * w + vrow) * Sn + kt * 64 + vchk], &Vl[1024 * w]);
    g2l(&vgb[(size_t)(16 * w + 8 + vrow) * Sn + kt * 64 + vchk],
        &Vl[1024 * w + 512]);
    __syncthreads();
    // S^T: sc[j] rows = k-cols 16j+4qd+r, col = q = cc
    fvec4 sc[4];
#pragma unroll
    for (int j = 0; j < 4; ++j) {
      int rk = 16 * j + cc;
      bvec8 b0 = *(const bvec8*)&Kd[rk * 64 + 8 * (qd ^ (cc & 7))];
      bvec8 b1 = *(const bvec8*)&Kd[rk * 64 + 8 * ((qd + 4) ^ (cc & 7))];
      fvec4 zz = {0.f, 0.f, 0.f, 0.f};
      zz = MFMA(b0, aq0, zz);
      sc[j] = MFMA(b1, aq1, zz);
    }
    // fixed-offset softmax: p = e^(s-16); common factor cancels in O/l.
    // 4 consecutive k per (j): pack into one b64 store to row-major Ps[q][k].
#pragma unroll
    for (int j = 0; j < 4; ++j) {
      float p0 = __builtin_amdgcn_exp2f(fmaf(sc[j][0], L2E, -NB));
      float p1 = __builtin_amdgcn_exp2f(fmaf(sc[j][1], L2E, -NB));
      float p2 = __builtin_amdgcn_exp2f(fmaf(sc[j][2], L2E, -NB));
      float p3 = __builtin_amdgcn_exp2f(fmaf(sc[j][3], L2E, -NB));
      l_s += (p0 + p1) + (p2 + p3);
      ushort4 u;
      u.x = f2b(p0); u.y = f2b(p1); u.z = f2b(p2); u.w = f2b(p3);
      *(ushort4*)&Ps[w][cc][16 * j + 4 * qd] = u;
    }
    bvec8 ap0 = *(const bvec8*)&Ps[w][cc][8 * qd];
    bvec8 ap1 = *(const bvec8*)&Ps[w][cc][32 + 8 * qd];
#pragma unroll
    for (int j = 0; j < 4; ++j) {
      int rv = 16 * j + cc;
      bvec8 v0 = *(const bvec8*)&Vl[rv * 64 + 8 * (qd ^ (cc & 7))];
      bvec8 v1 = *(const bvec8*)&Vl[rv * 64 + 8 * ((qd + 4) ^ (cc & 7))];
      O[j] = MFMA(ap0, v0, O[j]);
      O[j] = MFMA(ap1, v1, O[j]);
    }
  }
  // complete l for q=cc (sum the 4 quad partials), then fetch per-row inv
  l_s += __shfl_xor(l_s, 16);
  l_s += __shfl_xor(l_s, 32);
  float linv = 1.f / l_s;
  float inv[4];
#pragma unroll
  for (int r = 0; r < 4; ++r) inv[r] = __shfl(linv, 4 * qd + r);
#pragma unroll
  for (int j = 0; j < 4; ++j)
#pragma unroll
    for (int r = 0; r < 4; ++r) {
      int row = qt * 64 + w * 16 + 4 * qd + r;
      float* p = AT + ((size_t)(b * Sn + row)) * Dn + h * DKn + 16 * j + cc;
      *p += O[j][r] * inv[r];
    }
}

// ---------------- launch ----------------
extern "C" void kernel_launch(void* const* d_in, const int* in_sizes, int n_in,
                              void* d_out, int out_size, void* d_ws,
                              size_t ws_size, hipStream_t stream) {
  const float* x = (const float*)d_in[0];
  const float* Wq = (const float*)d_in[1];
  const float* Wk = (const float*)d_in[2];
  const float* Wv = (const float*)d_in[3];
  const float* Wo = (const float*)d_in[4];
  const float* traces = (const float*)d_in[5];
  const float* vtr = (const float*)d_in[6];
  const float* Wexp = (const float*)d_in[7];

  const size_t NQ = (size_t)Bn * Hn * Sn * DKn;  // 4,194,304
  unsigned short* Qb = (unsigned short*)d_ws;
  unsigned short* Kb = Qb + NQ;
  unsigned short* Vt = Kb + NQ;                // (bh, dk, s) bf16
  unsigned short* Wt = Vt + NQ;                // 4 x D*D bf16 = NQ shorts
  unsigned short* Mt = Wt + NQ;                // 16*64*64 = 65536
  unsigned short* WexpT = Mt + 65536;          // 256*64 = 16384
  unsigned short* VTt = WexpT + 16384;         // 16*64*256 = 262144
  float* alph = (float*)(VTt + 262144);        // 32 floats
  float* AT = alph + 32;                       // (B,S,D) fp32, 16MB
  unsigned short* xb = (unsigned short*)AT;    // aliased: dead before pattsep

  k_alphas<<<32, 256, 0, stream>>>(traces, vtr, alph);
  k_trW<<<dim3(16, 16, 4), 256, 0, stream>>>(Wq, Wk, Wv, Wo, Wt);
  k_mkM<<<16, 256, 0, stream>>>(traces, alph, Mt);
  k_trE<<<4, 256, 0, stream>>>(Wexp, WexpT);
  k_trVT<<<dim3(4, 16), 256, 0, stream>>>(vtr, VTt);
  k_xb<<<4096, 256, 0, stream>>>(x, xb);
  k_gemm<0><<<dim3(8, 32, 3), 256, 0, stream>>>(xb, nullptr, Wt, Qb, Kb, Vt,
                                                nullptr);
  k_pattsep<<<dim3(16, 32), 256, 0, stream>>>(Qb, WexpT, VTt, alph, AT);
  k_attn<<<dim3(32, 32), 256, 0, stream>>>(Qb, Kb, Vt, Mt, AT);
  k_gemm<1><<<dim3(8, 32, 1), 256, 0, stream>>>(
      nullptr, AT, Wt + 3 * (size_t)Dn * Dn, nullptr, nullptr, nullptr,
      (float*)d_out);
}